// Round 14
// baseline (253.490 us; speedup 1.0000x reference)
//
#include <hip/hip_runtime.h>
#include <math.h>

// Problem constants
#define BB   2
#define SS   2048
#define DD   1024
#define HH   16
#define DH   64
#define CBS  32
#define STRIDEC 16
#define NBLK 127          // (S - CBS)/STRIDE + 1
#define NSEL 16
#define WIN  16
#define NW   33           // 2*WIN+1
#define SCALE 0.125f      // DH^-0.5
#define MC   254          // BB * NBLK

typedef _Float16 f16;
typedef __attribute__((ext_vector_type(8))) _Float16 f16x8;
typedef __attribute__((ext_vector_type(4))) _Float16 f16x4;
typedef __attribute__((ext_vector_type(2))) _Float16 h2;
typedef __attribute__((ext_vector_type(4))) float f32x4;

// ---------------------------------------------------------------------------
// fp32 -> f16 elementwise convert (float4 loads, 4 elems/thread)
// ---------------------------------------------------------------------------
__global__ __launch_bounds__(256) void convert_f16(
    const float* __restrict__ src, f16* __restrict__ dst, int n)
{
    const int i = (blockIdx.x * 256 + threadIdx.x) * 4;
    if (i >= n) return;
    float4 v = *(const float4*)(src + i);
    f16x4 o;
    o[0] = (f16)v.x; o[1] = (f16)v.y; o[2] = (f16)v.z; o[3] = (f16)v.w;
    *(f16x4*)(dst + i) = o;
}

// ---------------------------------------------------------------------------
// fp32 (K x N) -> f16 (N x K) transpose-convert, 32x32 LDS tiles.
// Streams at ~6 TB/s (tiny blocks, no barrier-per-K-step) — used for
// qkv_w, out_w AND c1_w (un-fused again: the fused fp32-B gemm_c1 was
// stuck at 1.6 TB/s across four structural variants, R10-R13).
// ---------------------------------------------------------------------------
__global__ __launch_bounds__(256) void transpose_conv(
    const float* __restrict__ src, f16* __restrict__ dst, int K, int N)
{
    __shared__ float t[32][33];
    const int n0 = blockIdx.x * 32, k0 = blockIdx.y * 32;
    const int tx = threadIdx.x & 31, ty = threadIdx.x >> 5;   // 32 x 8
#pragma unroll
    for (int r = 0; r < 32; r += 8)
        t[ty + r][tx] = src[(size_t)(k0 + ty + r) * N + n0 + tx];
    __syncthreads();
#pragma unroll
    for (int r = 0; r < 32; r += 8)
        dst[(size_t)(n0 + ty + r) * K + k0 + tx] = (f16)t[tx][ty + r];
}

// ---------------------------------------------------------------------------
// f16 MFMA GEMM, m97-style: 128x128 tile, BK=64, 4 waves (2x2).  XCD-aware
// block swizzle (grid totals 768 / 256, both % 8 == 0) — R9 best config.
// ---------------------------------------------------------------------------
template<int OUT16>
__global__ __launch_bounds__(256) void gemm_f16(
    const f16* __restrict__ A, const f16* __restrict__ Bt,
    const float* __restrict__ bias, float* __restrict__ C,
    int M, int N, int K)
{
    constexpr int BK = 64;
    __shared__ f16 As[128 * BK];
    __shared__ f16 Bs[128 * BK];
    const int tid  = threadIdx.x;
    const int wid  = tid >> 6, lane = tid & 63;

    int lin = blockIdx.y * gridDim.x + blockIdx.x;
    const int nb = gridDim.x * gridDim.y;
    lin = (lin & 7) * (nb >> 3) + (lin >> 3);
    const int bx = lin % gridDim.x, by = lin / gridDim.x;

    const int bm = by * 128, bn = bx * 128;
    const int wm = (wid >> 1) * 64, wn = (wid & 1) * 64;

    const int lrow = lane >> 3;        // 0..7 (row within 8-row segment)
    const int lk8  = (lane & 7) * 8;   // k-element offset of this lane's 16B

    f32x4 acc[4][4];
#pragma unroll
    for (int i = 0; i < 4; ++i)
#pragma unroll
        for (int j = 0; j < 4; ++j) acc[i][j] = (f32x4){0.f, 0.f, 0.f, 0.f};

    for (int kt = 0; kt < K; kt += BK) {
#pragma unroll
        for (int c = 0; c < 4; ++c) {
            const int seg = c * 4 + wid;            // 0..15 -> rows seg*8..+8
            const int row = seg * 8 + lrow;
            const f16* ga = A + (size_t)(bm + row) * K + kt + lk8;
            __builtin_amdgcn_global_load_lds(
                (const __attribute__((address_space(1))) void*)(const void*)ga,
                (__attribute__((address_space(3))) void*)(void*)(As + seg * 512),
                16, 0, 0);
            const f16* gb = Bt + (size_t)(bn + row) * K + kt + lk8;
            __builtin_amdgcn_global_load_lds(
                (const __attribute__((address_space(1))) void*)(const void*)gb,
                (__attribute__((address_space(3))) void*)(void*)(Bs + seg * 512),
                16, 0, 0);
        }
        __syncthreads();   // compiler drains vmcnt before s_barrier

#pragma unroll
        for (int kk = 0; kk < 2; ++kk) {
            const int ko = kk * 32 + (lane >> 4) * 8;
            f16x8 a[4], b[4];
#pragma unroll
            for (int i = 0; i < 4; ++i)
                a[i] = *(const f16x8*)(As + (wm + i * 16 + (lane & 15)) * BK + ko);
#pragma unroll
            for (int j = 0; j < 4; ++j)
                b[j] = *(const f16x8*)(Bs + (wn + j * 16 + (lane & 15)) * BK + ko);
#pragma unroll
            for (int i = 0; i < 4; ++i)
#pragma unroll
                for (int j = 0; j < 4; ++j)
                    acc[i][j] = __builtin_amdgcn_mfma_f32_16x16x32_f16(
                        a[i], b[j], acc[i][j], 0, 0, 0);
        }
        __syncthreads();
    }

    const int rr0 = (lane >> 4) * 4;
    const int cc  = lane & 15;
#pragma unroll
    for (int i = 0; i < 4; ++i) {
        const int r = bm + wm + i * 16 + rr0;
#pragma unroll
        for (int j = 0; j < 4; ++j) {
            const int cn = bn + wn + j * 16 + cc;
            const float bv = bias[cn];
#pragma unroll
            for (int q = 0; q < 4; ++q) {
                if constexpr (OUT16)
                    ((f16*)C)[(size_t)(r + q) * N + cn] = (f16)(acc[i][j][q] + bv);
                else
                    C[(size_t)(r + q) * N + cn] = acc[i][j][q] + bv;
            }
        }
    }
}

// ---------------------------------------------------------------------------
// c1 compression GEMM — R6's proven pure-f16 version.  Reads PRE-TRANSPOSED
// WTc1 (N x K f16, L3-warm: just written by transpose_conv) via
// global_load_lds.  24 KB LDS -> 5-6 blocks/CU.  Grid (16, 2, 16).
// ---------------------------------------------------------------------------
#define C1_NZ 16
#define C1_KCHUNK 2048     // 32768 / 16

__global__ __launch_bounds__(256) void gemm_c1(
    const f16* __restrict__ xh, const f16* __restrict__ Wt,
    float* __restrict__ P)
{
    constexpr int BK = 64;
    __shared__ f16 As[128 * BK];   // 16 KB
    __shared__ f16 Bs[64 * BK];    //  8 KB
    const int tid  = threadIdx.x;
    const int wid  = tid >> 6, lane = tid & 63;
    const int bn = blockIdx.x * 64, bm = blockIdx.y * 128;
    const int z  = blockIdx.z;
    const int wm = (wid >> 1) * 64, wn = (wid & 1) * 32;

    const int lrow = lane >> 3;
    const int lk8  = (lane & 7) * 8;

    f32x4 acc[4][2];
#pragma unroll
    for (int i = 0; i < 4; ++i)
#pragma unroll
        for (int j = 0; j < 2; ++j) acc[i][j] = (f32x4){0.f, 0.f, 0.f, 0.f};

    for (int t = 0; t < C1_KCHUNK / BK; ++t) {
        const int ktg = z * C1_KCHUNK + t * BK;
        const int kc  = (ktg + lk8) >> 10;       // x feature-row within block
        const int kd  = (ktg + lk8) & 1023;      // x col
#pragma unroll
        for (int c = 0; c < 4; ++c) {
            const int seg = c * 4 + wid;
            int row = bm + seg * 8 + lrow;
            if (row > MC - 1) row = MC - 1;       // pad rows 254/255 (dup, unstored)
            const int b   = (row >= NBLK) ? 1 : 0;
            const int blk = row - b * NBLK;
            const f16* ga = xh + ((size_t)(b * SS + blk * STRIDEC + kc) << 10) + kd;
            __builtin_amdgcn_global_load_lds(
                (const __attribute__((address_space(1))) void*)(const void*)ga,
                (__attribute__((address_space(3))) void*)(void*)(As + seg * 512),
                16, 0, 0);
        }
#pragma unroll
        for (int c = 0; c < 2; ++c) {
            const int seg = wid * 2 + c;
            const int row = bn + seg * 8 + lrow;
            const f16* gb = Wt + (size_t)row * (CBS * DD) + ktg + lk8;
            __builtin_amdgcn_global_load_lds(
                (const __attribute__((address_space(1))) void*)(const void*)gb,
                (__attribute__((address_space(3))) void*)(void*)(Bs + seg * 512),
                16, 0, 0);
        }
        __syncthreads();

#pragma unroll
        for (int kk = 0; kk < 2; ++kk) {
            const int ko = kk * 32 + (lane >> 4) * 8;
            f16x8 a[4], b[2];
#pragma unroll
            for (int i = 0; i < 4; ++i)
                a[i] = *(const f16x8*)(As + (wm + i * 16 + (lane & 15)) * BK + ko);
#pragma unroll
            for (int j = 0; j < 2; ++j)
                b[j] = *(const f16x8*)(Bs + (wn + j * 16 + (lane & 15)) * BK + ko);
#pragma unroll
            for (int i = 0; i < 4; ++i)
#pragma unroll
                for (int j = 0; j < 2; ++j)
                    acc[i][j] = __builtin_amdgcn_mfma_f32_16x16x32_f16(
                        a[i], b[j], acc[i][j], 0, 0, 0);
        }
        __syncthreads();
    }

    const int rr0 = (lane >> 4) * 4;
    const int cc  = lane & 15;
#pragma unroll
    for (int i = 0; i < 4; ++i) {
        const int r = bm + wm + i * 16 + rr0;
#pragma unroll
        for (int j = 0; j < 2; ++j) {
            const int cn = bn + wn + j * 16 + cc;
#pragma unroll
            for (int q = 0; q < 4; ++q)
                if (r + q < MC)
                    P[((size_t)z * MC + r + q) * DD + cn] = acc[i][j][q];
        }
    }
}

// ---------------------------------------------------------------------------
// fp32 tiled GEMM 128x128 — small fp32-exact kernels: compSel (MODE 2,
// gather rows of `hidden` by topIdx) and sqkv (MODE 0), split-K partials.
// ---------------------------------------------------------------------------
template<int MODE>
__global__ __launch_bounds__(256) void gemm128(
    const float* __restrict__ A, const float* __restrict__ Bm,
    const float* __restrict__ bias, float* __restrict__ C,
    int M, int N, int K, const int* __restrict__ selIdx, int flags)
{
    __shared__ float As[8][132];
    __shared__ float Bs[8][132];

    const int tid = threadIdx.x;
    const int bm = blockIdx.y * 128;
    const int bn = blockIdx.x * 128;
    const int nz = gridDim.z;
    const int z  = blockIdx.z;
    const int kchunk = K / nz;
    const int k0 = z * kchunk;
    const int kend = k0 + kchunk;

    const int tx = tid & 15;
    const int ty = tid >> 4;

    const int arow = tid >> 1;
    const int akq  = (tid & 1) * 4;
    const int bkr  = tid >> 5;
    const int bcol = (tid & 31) * 4;

    float acc[2][2][4][4];
#pragma unroll
    for (int qi = 0; qi < 2; ++qi)
#pragma unroll
        for (int qj = 0; qj < 2; ++qj)
#pragma unroll
            for (int i = 0; i < 4; ++i)
#pragma unroll
                for (int j = 0; j < 4; ++j) acc[qi][qj][i][j] = 0.f;

    auto loadA = [&](int kt) -> float4 {
        float4 av = make_float4(0.f, 0.f, 0.f, 0.f);
        const int grow = bm + arow;
        if (grow < M) {
            if constexpr (MODE == 0) {
                av = *(const float4*)(A + (size_t)grow * K + kt + akq);
            } else {
                const int b = grow >> 4;
                const int j = grow & 15;
                const int idx = selIdx[b * NSEL + j];
                av = *(const float4*)(A + (size_t)(b * NBLK + idx) * K + kt + akq);
            }
        }
        return av;
    };
    auto loadB = [&](int kt) -> float4 {
        return *(const float4*)(Bm + (size_t)(kt + bkr) * N + bn + bcol);
    };

    float4 av = loadA(k0);
    float4 bv = loadB(k0);

    for (int kt = k0; kt < kend; kt += 8) {
        As[akq + 0][arow] = av.x;
        As[akq + 1][arow] = av.y;
        As[akq + 2][arow] = av.z;
        As[akq + 3][arow] = av.w;
        *(float4*)&Bs[bkr][bcol] = bv;
        __syncthreads();
        if (kt + 8 < kend) {
            av = loadA(kt + 8);
            bv = loadB(kt + 8);
        }
#pragma unroll
        for (int k = 0; k < 8; ++k) {
            const float4 a0 = *(const float4*)&As[k][ty * 4];
            const float4 a1 = *(const float4*)&As[k][64 + ty * 4];
            const float4 b0 = *(const float4*)&Bs[k][tx * 4];
            const float4 b1 = *(const float4*)&Bs[k][64 + tx * 4];
            const float ar[2][4] = {{a0.x, a0.y, a0.z, a0.w},
                                    {a1.x, a1.y, a1.z, a1.w}};
            const float br[2][4] = {{b0.x, b0.y, b0.z, b0.w},
                                    {b1.x, b1.y, b1.z, b1.w}};
#pragma unroll
            for (int qi = 0; qi < 2; ++qi)
#pragma unroll
                for (int i = 0; i < 4; ++i)
#pragma unroll
                    for (int qj = 0; qj < 2; ++qj)
#pragma unroll
                        for (int j = 0; j < 4; ++j)
                            acc[qi][qj][i][j] += ar[qi][i] * br[qj][j];
        }
        __syncthreads();
    }

    if (nz == 1) {
        const bool hasB   = (flags & 1) != 0;
        const bool doRelu = (flags & 2) != 0;
#pragma unroll
        for (int qi = 0; qi < 2; ++qi)
#pragma unroll
            for (int i = 0; i < 4; ++i) {
                const int r = bm + qi * 64 + ty * 4 + i;
                if (r >= M) continue;
#pragma unroll
                for (int qj = 0; qj < 2; ++qj)
#pragma unroll
                    for (int j = 0; j < 4; ++j) {
                        const int cn = bn + qj * 64 + tx * 4 + j;
                        float v = acc[qi][qj][i][j];
                        if (hasB) v += bias[cn];
                        if (doRelu) v = fmaxf(v, 0.f);
                        C[(size_t)r * N + cn] = v;
                    }
            }
    } else {
        float* P = C + (size_t)z * M * N;
#pragma unroll
        for (int qi = 0; qi < 2; ++qi)
#pragma unroll
            for (int i = 0; i < 4; ++i) {
                const int r = bm + qi * 64 + ty * 4 + i;
                if (r >= M) continue;
#pragma unroll
                for (int qj = 0; qj < 2; ++qj)
#pragma unroll
                    for (int j = 0; j < 4; ++j) {
                        const int cn = bn + qj * 64 + tx * 4 + j;
                        P[(size_t)r * N + cn] = acc[qi][qj][i][j];
                    }
            }
    }
}

// Sum split-K partials + bias (+relu); halfOut -> write f16
__global__ __launch_bounds__(256) void reduce_partials(
    const float* __restrict__ P, const float* __restrict__ bias,
    float* __restrict__ outp, int MN, int N, int nz, int doRelu, int halfOut)
{
    const int i = blockIdx.x * 256 + threadIdx.x;
    if (i >= MN) return;
    float s = 0.f;
    for (int z = 0; z < nz; ++z) s += P[(size_t)z * MN + i];
    s += bias[i % N];
    if (doRelu) s = fmaxf(s, 0.f);
    if (halfOut) ((f16*)outp)[i] = (f16)s;
    else         outp[i] = s;
}

// w2s[k] = c2_w[k,:] . score_w   (row-dot; one block per k, coalesced)
__global__ __launch_bounds__(256) void w2s_kernel(
    const float* __restrict__ c2w, const float* __restrict__ sw,
    float* __restrict__ w2s)
{
    const int k = blockIdx.x;
    const float* rp = c2w + (size_t)k * DD;
    float s = 0.f;
    for (int n = threadIdx.x; n < DD; n += 256) s += rp[n] * sw[n];
#pragma unroll
    for (int off = 32; off >= 1; off >>= 1) s += __shfl_xor(s, off);
    __shared__ float red[4];
    if ((threadIdx.x & 63) == 0) red[threadIdx.x >> 6] = s;
    __syncthreads();
    if (threadIdx.x == 0) w2s[k] = red[0] + red[1] + red[2] + red[3];
}

// scores[row] = hidden[row,:] . w2s   (constant offset dropped: rank-invariant)
__global__ __launch_bounds__(256) void score2_kernel(
    const float* __restrict__ hidden, const float* __restrict__ w2s,
    float* __restrict__ scores)
{
    const int row = blockIdx.x;
    const float* hp = hidden + (size_t)row * DD;
    float s = 0.f;
    for (int k = threadIdx.x; k < DD; k += 256) s += hp[k] * w2s[k];
#pragma unroll
    for (int off = 32; off >= 1; off >>= 1) s += __shfl_xor(s, off);
    __shared__ float red[4];
    if ((threadIdx.x & 63) == 0) red[threadIdx.x >> 6] = s;
    __syncthreads();
    if (threadIdx.x == 0) scores[row] = red[0] + red[1] + red[2] + red[3];
}

// top-16 of 127 scores per batch (set semantics; lowest-index tie-break)
__global__ __launch_bounds__(128) void topk_kernel(
    const float* __restrict__ scores, int* __restrict__ top)
{
    const int b = blockIdx.x;
    const int t = threadIdx.x;  // 128
    __shared__ float sval[128];
    __shared__ float sv2[128];
    __shared__ int   si2[128];
    __shared__ unsigned char used[128];
    sval[t] = (t < NBLK) ? scores[b * NBLK + t] : -INFINITY;
    used[t] = 0;
    __syncthreads();
    for (int j = 0; j < NSEL; ++j) {
        sv2[t] = used[t] ? -INFINITY : sval[t];
        si2[t] = t;
        __syncthreads();
        for (int stp = 64; stp >= 1; stp >>= 1) {
            if (t < stp) {
                if (sv2[t + stp] > sv2[t] ||
                    (sv2[t + stp] == sv2[t] && si2[t + stp] < si2[t])) {
                    sv2[t] = sv2[t + stp];
                    si2[t] = si2[t + stp];
                }
            }
            __syncthreads();
        }
        if (t == 0) { top[b * NSEL + j] = si2[0]; used[si2[0]] = 1; }
        __syncthreads();
    }
}

// ---------------------------------------------------------------------------
// Attention (MFMA, f16 I/O): block = 4 waves, one (b,h,64-query tile).
// ---------------------------------------------------------------------------
#define QT 64
#define KROWS 96   // QT + 2*WIN
#define KST2 72    // K/sK row stride in halves (144 B)
#define VST 136    // Vt row stride in halves
#define PST 136    // P row stride in halves

__global__ __launch_bounds__(256) void attn_mfma(
    const f16* __restrict__ qkv, const f16* __restrict__ sqkv,
    f16* __restrict__ attn)
{
    __shared__ f16 Kl[KROWS][KST2];      // 13824 B
    __shared__ f16 sKl[NSEL][KST2];      //  2304 B
    __shared__ f16 Vt[DH][VST];          // 17408 B  (cols: 0..95 win, 96..111 sel, 112..127 zero)
    __shared__ f16 Pl[4][16][PST];       // 17408 B  per-wave P[q16][kv128]

    int bid = blockIdx.x;
    bid = (bid & 7) * (gridDim.x >> 3) + (bid >> 3);   // XCD swizzle (1024%8==0)
    const int t = bid & 31;
    const int h = (bid >> 5) & (HH - 1);
    const int b = bid >> 9;
    const int s0 = t * QT;

    const int tid = threadIdx.x;
    const int wid = tid >> 6, lane = tid & 63;
    const int l15 = lane & 15, lg = lane >> 4;

    // ---- stage K rows + V transposed ----
    for (int i = tid; i < KROWS * 8; i += 256) {
        const int row = i >> 3, c8 = (i & 7) * 8;
        const int pos = s0 - WIN + row;
        f16x8 kv, vv;
#pragma unroll
        for (int u = 0; u < 8; ++u) { kv[u] = (f16)0.f; vv[u] = (f16)0.f; }
        if (pos >= 0 && pos < SS) {
            const f16* base = qkv + (size_t)(b * SS + pos) * (3 * DD) + h * DH + c8;
            kv = *(const f16x8*)(base + DD);
            vv = *(const f16x8*)(base + 2 * DD);
        }
        *(f16x8*)&Kl[row][c8] = kv;
#pragma unroll
        for (int u = 0; u < 8; ++u) Vt[c8 + u][row] = vv[u];
    }
    // ---- stage sel K/V ----
    if (tid < NSEL * 8) {
        const int si = tid >> 3, c8 = (tid & 7) * 8;
        const f16* base = sqkv + (size_t)(b * NSEL + si) * (3 * DD) + h * DH + c8;
        f16x8 kv = *(const f16x8*)(base + DD);
        f16x8 vv = *(const f16x8*)(base + 2 * DD);
        *(f16x8*)&sKl[si][c8] = kv;
#pragma unroll
        for (int u = 0; u < 8; ++u) Vt[c8 + u][96 + si] = vv[u];
    }
    // ---- zero Vt kv columns 112..127 ----
    for (int i = tid; i < DH * 16; i += 256)
        Vt[i >> 4][112 + (i & 15)] = (f16)0.f;

    // ---- Q fragments: raw f16x8 loads ----
    f16x8 qf[2];
    {
        const f16* qp = qkv + (size_t)(b * SS + s0 + wid * 16 + l15) * (3 * DD)
                      + h * DH + lg * 8;
        qf[0] = *(const f16x8*)(qp);
        qf[1] = *(const f16x8*)(qp + 32);
    }
    __syncthreads();

    // ---- QK^T swapped: D[kv][q] ----
    f32x4 aqk[6], asel;
#pragma unroll
    for (int i = 0; i < 6; ++i) aqk[i] = (f32x4){0.f, 0.f, 0.f, 0.f};
    asel = (f32x4){0.f, 0.f, 0.f, 0.f};
#pragma unroll
    for (int kc = 0; kc < 2; ++kc) {
        const int ko = kc * 32 + lg * 8;
#pragma unroll
        for (int kvb = 0; kvb < 6; ++kvb) {
            f16x8 ka = *(const f16x8*)&Kl[kvb * 16 + l15][ko];
            aqk[kvb] = __builtin_amdgcn_mfma_f32_16x16x32_f16(ka, qf[kc], aqk[kvb], 0, 0, 0);
        }
        f16x8 ks = *(const f16x8*)&sKl[l15][ko];
        asel = __builtin_amdgcn_mfma_f32_16x16x32_f16(ks, qf[kc], asel, 0, 0, 0);
    }

    // ---- local softmax ----
    const int qt_ = wid * 16 + l15;
    float sc[6][4];
    float m = -INFINITY;
#pragma unroll
    for (int kvb = 0; kvb < 6; ++kvb)
#pragma unroll
        for (int r = 0; r < 4; ++r) {
            const int kv  = kvb * 16 + lg * 4 + r;
            const int pos = s0 - WIN + kv;
            const int dlt = kv - qt_;
            const bool ok = (dlt >= 0) & (dlt <= 32) & (pos >= 0) & (pos < SS);
            sc[kvb][r] = ok ? aqk[kvb][r] * SCALE : -INFINITY;
            m = fmaxf(m, sc[kvb][r]);
        }
    m = fmaxf(m, __shfl_xor(m, 16));
    m = fmaxf(m, __shfl_xor(m, 32));
    float sum = 0.f;
#pragma unroll
    for (int kvb = 0; kvb < 6; ++kvb)
#pragma unroll
        for (int r = 0; r < 4; ++r) {
            sc[kvb][r] = __expf(sc[kvb][r] - m);
            sum += sc[kvb][r];
        }
    sum += __shfl_xor(sum, 16);
    sum += __shfl_xor(sum, 32);
    const float inv1 = 1.f / sum;

    // ---- sel softmax ----
    float s2[4];
    float m2 = -INFINITY;
#pragma unroll
    for (int r = 0; r < 4; ++r) { s2[r] = asel[r] * SCALE; m2 = fmaxf(m2, s2[r]); }
    m2 = fmaxf(m2, __shfl_xor(m2, 16));
    m2 = fmaxf(m2, __shfl_xor(m2, 32));
    float sum2 = 0.f;
#pragma unroll
    for (int r = 0; r < 4; ++r) { s2[r] = __expf(s2[r] - m2); sum2 += s2[r]; }
    sum2 += __shfl_xor(sum2, 16);
    sum2 += __shfl_xor(sum2, 32);
    const float inv2 = 1.f / sum2;

    // ---- write P (pre-normalized); Pl is wave-private -> no barrier ----
#pragma unroll
    for (int kvb = 0; kvb < 6; ++kvb) {
        h2 p01, p23;
        p01[0] = (f16)(sc[kvb][0] * inv1); p01[1] = (f16)(sc[kvb][1] * inv1);
        p23[0] = (f16)(sc[kvb][2] * inv1); p23[1] = (f16)(sc[kvb][3] * inv1);
        *(h2*)&Pl[wid][l15][kvb * 16 + lg * 4]     = p01;
        *(h2*)&Pl[wid][l15][kvb * 16 + lg * 4 + 2] = p23;
    }
    {
        h2 g01, g23, z0;
        g01[0] = (f16)(s2[0] * inv2); g01[1] = (f16)(s2[1] * inv2);
        g23[0] = (f16)(s2[2] * inv2); g23[1] = (f16)(s2[3] * inv2);
        z0[0] = (f16)0.f; z0[1] = (f16)0.f;
        *(h2*)&Pl[wid][l15][96 + lg * 4]      = g01;
        *(h2*)&Pl[wid][l15][96 + lg * 4 + 2]  = g23;
        *(h2*)&Pl[wid][l15][112 + lg * 4]     = z0;
        *(h2*)&Pl[wid][l15][112 + lg * 4 + 2] = z0;
    }

    // ---- PV: O[q][d] = P[q][kv] . Vt[d][kv] ----
    f32x4 ov[4];
#pragma unroll
    for (int i = 0; i < 4; ++i) ov[i] = (f32x4){0.f, 0.f, 0.f, 0.f};
#pragma unroll
    for (int kc = 0; kc < 4; ++kc) {
        const int ko = kc * 32 + lg * 8;
        f16x8 pa = *(const f16x8*)&Pl[wid][l15][ko];
#pragma unroll
        for (int db = 0; db < 4; ++db) {
            f16x8 vb = *(const f16x8*)&Vt[db * 16 + l15][ko];
            ov[db] = __builtin_amdgcn_mfma_f32_16x16x32_f16(pa, vb, ov[db], 0, 0, 0);
        }
    }

    // ---- store O ----
    const size_t rbase = (size_t)(b * SS + s0 + wid * 16 + lg * 4);
#pragma unroll
    for (int r = 0; r < 4; ++r) {
        f16* op = attn + (rbase + r) * DD + h * DH + l15;
#pragma unroll
        for (int db = 0; db < 4; ++db)
            op[db * 16] = (f16)ov[db][r];
    }
}

extern "C" void kernel_launch(void* const* d_in, const int* in_sizes, int n_in,
                              void* d_out, int out_size, void* d_ws, size_t ws_size,
                              hipStream_t stream)
{
    const float* x       = (const float*)d_in[0];
    const float* qkv_w   = (const float*)d_in[1];
    const float* qkv_b   = (const float*)d_in[2];
    const float* c1_w    = (const float*)d_in[3];
    const float* c1_b    = (const float*)d_in[4];
    const float* c2_w    = (const float*)d_in[5];
    const float* c2_b    = (const float*)d_in[6];
    const float* score_w = (const float*)d_in[7];
    const float* score_b = (const float*)d_in[8];
    const float* out_w   = (const float*)d_in[9];
    const float* out_b   = (const float*)d_in[10];
    float* out = (float*)d_out;
    float* ws  = (float*)d_ws;
    (void)score_b;   // rank-invariant constant (c2_b.score_w + score_b) dropped

    // workspace layout (float units); fill evidence shows ws >= 134M floats
    f16*   xh      = (f16*)ws;                   // 4096x1024 halves
    float* A1      = ws + 2097152;
    f16*   qkvb    = (f16*)A1;                   // 4096x3072 halves
    f16*   attnf   = (f16*)(A1 + 12582912);      // 4096x1024 halves
    float* A2      = ws + 18874368;              // 4,161,536 floats scratch
    float* part    = A2;                         // split-K partials (<= 16x254x1024)
    float* hidden  = ws + 23035904;              // 260,096
    float* scores  = hidden + 260096;            // 256
    int*   topIdx  = (int*)(scores + 256);       // 32 ints
    float* sqkvb   = scores + 256 + 64;          // f16 region, 49,152 floats
    float* w2s     = sqkvb + 49152;              // 1024
    float* compSel = w2s + 1024;                 // 32 x 1024 fp32
    f16*   qkv_wT  = (f16*)(ws + 33000000);      // 3072x1024 halves (fresh)
    f16*   out_wT  = (f16*)(ws + 34600000);      // 1024x1024 halves (fresh)
    f16*   WTc1    = (f16*)(ws + 36000000);      // 1024x32768 halves (fresh, 16.78M floats)

    const int MROWS = BB * SS;        // 4096
    const int MSEL  = BB * NSEL;      // 32

    // 0. x -> f16
    convert_f16<<<(MROWS * DD) / (256 * 4), 256, 0, stream>>>(x, xh, MROWS * DD);

    // 0b. weight transposes.  c1_w transpose streams 201 MB at ~6 TB/s
    //     (vs the fused in-GEMM convert stuck at 1.6 TB/s, R10-R13) and
    //     leaves WTc1 L3-warm for gemm_c1.
    transpose_conv<<<dim3(3 * DD / 32, DD / 32), 256, 0, stream>>>(
        qkv_w, qkv_wT, DD, 3 * DD);
    transpose_conv<<<dim3(DD / 32, DD / 32), 256, 0, stream>>>(
        out_w, out_wT, DD, DD);
    transpose_conv<<<dim3(DD / 32, CBS * DD / 32), 256, 0, stream>>>(
        c1_w, WTc1, CBS * DD, DD);

    // 1. c1: hidden partials via pure-f16 MFMA (R6-proven), split-K 16
    gemm_c1<<<dim3(DD / 64, 2, C1_NZ), 256, 0, stream>>>(xh, WTc1, part);

    // 2. hidden = relu(sum partials + c1_b)  [fp32]
    reduce_partials<<<(MC * DD) / 256, 256, 0, stream>>>(
        part, c1_b, hidden, MC * DD, DD, C1_NZ, 1, 0);

    // 3. w2s = c2_w @ score_w  (row-dots)
    w2s_kernel<<<DD, 256, 0, stream>>>(c2_w, score_w, w2s);

    // 4. scores = hidden @ w2s  (constant offset dropped; rank-invariant)
    score2_kernel<<<MC, 256, 0, stream>>>(hidden, w2s, scores);

    // 5. top-16 per batch
    topk_kernel<<<BB, 128, 0, stream>>>(scores, topIdx);

    // 6. compSel partials: hidden[sel] @ c2_w  (32 x 1024, K=1024, split-K 16)
    gemm128<2><<<dim3(DD / 128, 1, 16), 256, 0, stream>>>(
        hidden, c2_w, nullptr, part, MSEL, DD, DD, topIdx, 0);

    // 6b. compSel = sum partials + c2_b  [fp32]
    reduce_partials<<<(MSEL * DD) / 256, 256, 0, stream>>>(
        part, c2_b, compSel, MSEL * DD, DD, 16, 0, 0);

    // 7. sqkv partials: compSel @ qkv_w  (32 x 3072, K=1024, split-K 16)
    gemm128<0><<<dim3(3 * DD / 128, 1, 16), 256, 0, stream>>>(
        compSel, qkv_w, nullptr, part, MSEL, 3 * DD, DD, nullptr, 0);

    // 7b. sqkv = sum partials + qkv_b  [f16]
    reduce_partials<<<(MSEL * 3 * DD + 255) / 256, 256, 0, stream>>>(
        part, qkv_b, sqkvb, MSEL * 3 * DD, 3 * DD, 16, 0, 1);

    // 8. qkv = x @ qkv_w + qkv_b  [f16 MFMA, f16 out, XCD-swizzled]
    gemm_f16<1><<<dim3(3 * DD / 128, MROWS / 128), 256, 0, stream>>>(
        xh, qkv_wT, qkv_b, (float*)qkvb, MROWS, 3 * DD, DD);

    // 9. attention on matrix cores (f16 I/O)
    attn_mfma<<<BB * HH * (SS / QT), 256, 0, stream>>>(
        qkvb, (const f16*)sqkvb, attnf);

    // 10. out = attn @ out_w + out_b  [f16 MFMA, fp32 out]
    gemm_f16<0><<<dim3(DD / 128, MROWS / 128), 256, 0, stream>>>(
        attnf, out_wT, out_b, out, MROWS, DD, DD);
}

// Round 15
// 227.536 us; speedup vs baseline: 1.1141x; 1.1141x over previous
//
#include <hip/hip_runtime.h>
#include <math.h>

// Problem constants
#define BB   2
#define SS   2048
#define DD   1024
#define HH   16
#define DH   64
#define CBS  32
#define STRIDEC 16
#define NBLK 127          // (S - CBS)/STRIDE + 1
#define NSEL 16
#define WIN  16
#define NW   33           // 2*WIN+1
#define SCALE 0.125f      // DH^-0.5
#define MC   254          // BB * NBLK

typedef _Float16 f16;
typedef __attribute__((ext_vector_type(8))) _Float16 f16x8;
typedef __attribute__((ext_vector_type(4))) _Float16 f16x4;
typedef __attribute__((ext_vector_type(2))) _Float16 h2;
typedef __attribute__((ext_vector_type(4))) float f32x4;

// ---------------------------------------------------------------------------
// fp32 -> f16 elementwise convert (float4 loads, 4 elems/thread)
// ---------------------------------------------------------------------------
__global__ __launch_bounds__(256) void convert_f16(
    const float* __restrict__ src, f16* __restrict__ dst, int n)
{
    const int i = (blockIdx.x * 256 + threadIdx.x) * 4;
    if (i >= n) return;
    float4 v = *(const float4*)(src + i);
    f16x4 o;
    o[0] = (f16)v.x; o[1] = (f16)v.y; o[2] = (f16)v.z; o[3] = (f16)v.w;
    *(f16x4*)(dst + i) = o;
}

// ---------------------------------------------------------------------------
// fp32 (K x N) -> f16 (N x K) transpose-convert, 32x32 LDS tiles
// (qkv_w / out_w only; c1_w transpose stays fused in gemm_c1 — R14 proved
// un-fusing costs its full 32 us with no gemm_c1 gain)
// ---------------------------------------------------------------------------
__global__ __launch_bounds__(256) void transpose_conv(
    const float* __restrict__ src, f16* __restrict__ dst, int K, int N)
{
    __shared__ float t[32][33];
    const int n0 = blockIdx.x * 32, k0 = blockIdx.y * 32;
    const int tx = threadIdx.x & 31, ty = threadIdx.x >> 5;   // 32 x 8
#pragma unroll
    for (int r = 0; r < 32; r += 8)
        t[ty + r][tx] = src[(size_t)(k0 + ty + r) * N + n0 + tx];
    __syncthreads();
#pragma unroll
    for (int r = 0; r < 32; r += 8)
        dst[(size_t)(n0 + ty + r) * K + k0 + tx] = (f16)t[tx][ty + r];
}

// ---------------------------------------------------------------------------
// f16 MFMA GEMM, m97-style: 128x128 tile, BK=64, 4 waves (2x2).
// Plain blockIdx (swizzle removed: operands L3-resident; R10 deconfound +
// guide m160 both say the swizzle costs ~2% in this regime).
// ---------------------------------------------------------------------------
template<int OUT16>
__global__ __launch_bounds__(256) void gemm_f16(
    const f16* __restrict__ A, const f16* __restrict__ Bt,
    const float* __restrict__ bias, float* __restrict__ C,
    int M, int N, int K)
{
    constexpr int BK = 64;
    __shared__ f16 As[128 * BK];
    __shared__ f16 Bs[128 * BK];
    const int tid  = threadIdx.x;
    const int wid  = tid >> 6, lane = tid & 63;
    const int bm = blockIdx.y * 128, bn = blockIdx.x * 128;
    const int wm = (wid >> 1) * 64, wn = (wid & 1) * 64;

    const int lrow = lane >> 3;        // 0..7 (row within 8-row segment)
    const int lk8  = (lane & 7) * 8;   // k-element offset of this lane's 16B

    f32x4 acc[4][4];
#pragma unroll
    for (int i = 0; i < 4; ++i)
#pragma unroll
        for (int j = 0; j < 4; ++j) acc[i][j] = (f32x4){0.f, 0.f, 0.f, 0.f};

    for (int kt = 0; kt < K; kt += BK) {
#pragma unroll
        for (int c = 0; c < 4; ++c) {
            const int seg = c * 4 + wid;            // 0..15 -> rows seg*8..+8
            const int row = seg * 8 + lrow;
            const f16* ga = A + (size_t)(bm + row) * K + kt + lk8;
            __builtin_amdgcn_global_load_lds(
                (const __attribute__((address_space(1))) void*)(const void*)ga,
                (__attribute__((address_space(3))) void*)(void*)(As + seg * 512),
                16, 0, 0);
            const f16* gb = Bt + (size_t)(bn + row) * K + kt + lk8;
            __builtin_amdgcn_global_load_lds(
                (const __attribute__((address_space(1))) void*)(const void*)gb,
                (__attribute__((address_space(3))) void*)(void*)(Bs + seg * 512),
                16, 0, 0);
        }
        __syncthreads();   // compiler drains vmcnt before s_barrier

#pragma unroll
        for (int kk = 0; kk < 2; ++kk) {
            const int ko = kk * 32 + (lane >> 4) * 8;
            f16x8 a[4], b[4];
#pragma unroll
            for (int i = 0; i < 4; ++i)
                a[i] = *(const f16x8*)(As + (wm + i * 16 + (lane & 15)) * BK + ko);
#pragma unroll
            for (int j = 0; j < 4; ++j)
                b[j] = *(const f16x8*)(Bs + (wn + j * 16 + (lane & 15)) * BK + ko);
#pragma unroll
            for (int i = 0; i < 4; ++i)
#pragma unroll
                for (int j = 0; j < 4; ++j)
                    acc[i][j] = __builtin_amdgcn_mfma_f32_16x16x32_f16(
                        a[i], b[j], acc[i][j], 0, 0, 0);
        }
        __syncthreads();
    }

    const int rr0 = (lane >> 4) * 4;
    const int cc  = lane & 15;
#pragma unroll
    for (int i = 0; i < 4; ++i) {
        const int r = bm + wm + i * 16 + rr0;
#pragma unroll
        for (int j = 0; j < 4; ++j) {
            const int cn = bn + wn + j * 16 + cc;
            const float bv = bias[cn];
#pragma unroll
            for (int q = 0; q < 4; ++q) {
                if constexpr (OUT16)
                    ((f16*)C)[(size_t)(r + q) * N + cn] = (f16)(acc[i][j][q] + bv);
                else
                    C[(size_t)(r + q) * N + cn] = acc[i][j][q] + bv;
            }
        }
    }
}

// ---------------------------------------------------------------------------
// c1 compression GEMM (R9's fused version).  ONLY change: split-K 16 -> 32,
// grid (16,2,32) = 1024 blocks = 4 blocks/CU (was 2).  Blocks are NOT
// barrier-synced with each other, so co-resident blocks overlap one
// another's vmcnt-drain with MFMA — the residency lever R10-R14 missed.
// ---------------------------------------------------------------------------
#define C1_NZ 32
#define C1_KCHUNK 1024     // 32768 / 32

__global__ __launch_bounds__(256) void gemm_c1(
    const f16* __restrict__ xh, const float* __restrict__ c1w,
    float* __restrict__ P)
{
    constexpr int BK = 64;
    constexpr int BSTR = 72;          // halves (144 B rows)
    __shared__ f16 As[128 * BK];      // 16 KB
    __shared__ f16 Bs[64 * BSTR];     // 9216 B   -> 25.2 KB total
    const int tid  = threadIdx.x;
    const int wid  = tid >> 6, lane = tid & 63;
    const int bn = blockIdx.x * 64, bm = blockIdx.y * 128;
    const int z  = blockIdx.z;
    const int wm = (wid >> 1) * 64, wn = (wid & 1) * 32;

    const int lrow = lane >> 3;
    const int lk8  = (lane & 7) * 8;

    f32x4 acc[4][2];
#pragma unroll
    for (int i = 0; i < 4; ++i)
#pragma unroll
        for (int j = 0; j < 2; ++j) acc[i][j] = (f32x4){0.f, 0.f, 0.f, 0.f};

    for (int t = 0; t < C1_KCHUNK / BK; ++t) {   // 16 iterations
        const int ktg = z * C1_KCHUNK + t * BK;
        const int kc  = (ktg + lk8) >> 10;       // x feature-row within block
        const int kd  = (ktg + lk8) & 1023;      // x col
#pragma unroll
        for (int c = 0; c < 4; ++c) {
            const int seg = c * 4 + wid;
            int row = bm + seg * 8 + lrow;
            if (row > MC - 1) row = MC - 1;       // pad rows 254/255 (dup, unstored)
            const int b   = (row >= NBLK) ? 1 : 0;
            const int blk = row - b * NBLK;
            const f16* ga = xh + ((size_t)(b * SS + blk * STRIDEC + kc) << 10) + kd;
            __builtin_amdgcn_global_load_lds(
                (const __attribute__((address_space(1))) void*)(const void*)ga,
                (__attribute__((address_space(3))) void*)(void*)(As + seg * 512),
                16, 0, 0);
        }
        // stage B: fp32 c1_w (KxN) -> f16 transposed into Bs[n][kk], XOR swz
        {
            const int kk0 = (tid >> 4) * 2;       // 0..30 even
            const int n4  = (tid & 15) * 4;
#pragma unroll
            for (int p = 0; p < 2; ++p) {
                const int kk = kk0 + p * 32;
                const float* gB = c1w + (size_t)(ktg + kk) * DD + bn + n4;
                float4 r0 = *(const float4*)gB;
                float4 r1 = *(const float4*)(gB + DD);
                const float a0[4] = {r0.x, r0.y, r0.z, r0.w};
                const float a1[4] = {r1.x, r1.y, r1.z, r1.w};
#pragma unroll
                for (int u = 0; u < 4; ++u) {
                    const int n = n4 + u;
                    h2 w; w[0] = (f16)a0[u]; w[1] = (f16)a1[u];
                    *(h2*)&Bs[n * BSTR + (kk ^ (((n >> 3) & 3) << 3))] = w;
                }
            }
        }
        __syncthreads();

#pragma unroll
        for (int kk = 0; kk < 2; ++kk) {
            const int ko = kk * 32 + (lane >> 4) * 8;
            f16x8 a[4], b[2];
#pragma unroll
            for (int i = 0; i < 4; ++i)
                a[i] = *(const f16x8*)(As + (wm + i * 16 + (lane & 15)) * BK + ko);
#pragma unroll
            for (int j = 0; j < 2; ++j) {
                const int n = wn + j * 16 + (lane & 15);
                b[j] = *(const f16x8*)&Bs[n * BSTR + (ko ^ (((n >> 3) & 3) << 3))];
            }
#pragma unroll
            for (int i = 0; i < 4; ++i)
#pragma unroll
                for (int j = 0; j < 2; ++j)
                    acc[i][j] = __builtin_amdgcn_mfma_f32_16x16x32_f16(
                        a[i], b[j], acc[i][j], 0, 0, 0);
        }
        __syncthreads();
    }

    const int rr0 = (lane >> 4) * 4;
    const int cc  = lane & 15;
#pragma unroll
    for (int i = 0; i < 4; ++i) {
        const int r = bm + wm + i * 16 + rr0;
#pragma unroll
        for (int j = 0; j < 2; ++j) {
            const int cn = bn + wn + j * 16 + cc;
#pragma unroll
            for (int q = 0; q < 4; ++q)
                if (r + q < MC)
                    P[((size_t)z * MC + r + q) * DD + cn] = acc[i][j][q];
        }
    }
}

// ---------------------------------------------------------------------------
// fp32 tiled GEMM 128x128 — small fp32-exact kernels: compSel (MODE 2,
// gather rows of `hidden` by topIdx) and sqkv (MODE 0), split-K partials.
// ---------------------------------------------------------------------------
template<int MODE>
__global__ __launch_bounds__(256) void gemm128(
    const float* __restrict__ A, const float* __restrict__ Bm,
    const float* __restrict__ bias, float* __restrict__ C,
    int M, int N, int K, const int* __restrict__ selIdx, int flags)
{
    __shared__ float As[8][132];
    __shared__ float Bs[8][132];

    const int tid = threadIdx.x;
    const int bm = blockIdx.y * 128;
    const int bn = blockIdx.x * 128;
    const int nz = gridDim.z;
    const int z  = blockIdx.z;
    const int kchunk = K / nz;
    const int k0 = z * kchunk;
    const int kend = k0 + kchunk;

    const int tx = tid & 15;
    const int ty = tid >> 4;

    const int arow = tid >> 1;
    const int akq  = (tid & 1) * 4;
    const int bkr  = tid >> 5;
    const int bcol = (tid & 31) * 4;

    float acc[2][2][4][4];
#pragma unroll
    for (int qi = 0; qi < 2; ++qi)
#pragma unroll
        for (int qj = 0; qj < 2; ++qj)
#pragma unroll
            for (int i = 0; i < 4; ++i)
#pragma unroll
                for (int j = 0; j < 4; ++j) acc[qi][qj][i][j] = 0.f;

    auto loadA = [&](int kt) -> float4 {
        float4 av = make_float4(0.f, 0.f, 0.f, 0.f);
        const int grow = bm + arow;
        if (grow < M) {
            if constexpr (MODE == 0) {
                av = *(const float4*)(A + (size_t)grow * K + kt + akq);
            } else {
                const int b = grow >> 4;
                const int j = grow & 15;
                const int idx = selIdx[b * NSEL + j];
                av = *(const float4*)(A + (size_t)(b * NBLK + idx) * K + kt + akq);
            }
        }
        return av;
    };
    auto loadB = [&](int kt) -> float4 {
        return *(const float4*)(Bm + (size_t)(kt + bkr) * N + bn + bcol);
    };

    float4 av = loadA(k0);
    float4 bv = loadB(k0);

    for (int kt = k0; kt < kend; kt += 8) {
        As[akq + 0][arow] = av.x;
        As[akq + 1][arow] = av.y;
        As[akq + 2][arow] = av.z;
        As[akq + 3][arow] = av.w;
        *(float4*)&Bs[bkr][bcol] = bv;
        __syncthreads();
        if (kt + 8 < kend) {
            av = loadA(kt + 8);
            bv = loadB(kt + 8);
        }
#pragma unroll
        for (int k = 0; k < 8; ++k) {
            const float4 a0 = *(const float4*)&As[k][ty * 4];
            const float4 a1 = *(const float4*)&As[k][64 + ty * 4];
            const float4 b0 = *(const float4*)&Bs[k][tx * 4];
            const float4 b1 = *(const float4*)&Bs[k][64 + tx * 4];
            const float ar[2][4] = {{a0.x, a0.y, a0.z, a0.w},
                                    {a1.x, a1.y, a1.z, a1.w}};
            const float br[2][4] = {{b0.x, b0.y, b0.z, b0.w},
                                    {b1.x, b1.y, b1.z, b1.w}};
#pragma unroll
            for (int qi = 0; qi < 2; ++qi)
#pragma unroll
                for (int i = 0; i < 4; ++i)
#pragma unroll
                    for (int qj = 0; qj < 2; ++qj)
#pragma unroll
                        for (int j = 0; j < 4; ++j)
                            acc[qi][qj][i][j] += ar[qi][i] * br[qj][j];
        }
        __syncthreads();
    }

    if (nz == 1) {
        const bool hasB   = (flags & 1) != 0;
        const bool doRelu = (flags & 2) != 0;
#pragma unroll
        for (int qi = 0; qi < 2; ++qi)
#pragma unroll
            for (int i = 0; i < 4; ++i) {
                const int r = bm + qi * 64 + ty * 4 + i;
                if (r >= M) continue;
#pragma unroll
                for (int qj = 0; qj < 2; ++qj)
#pragma unroll
                    for (int j = 0; j < 4; ++j) {
                        const int cn = bn + qj * 64 + tx * 4 + j;
                        float v = acc[qi][qj][i][j];
                        if (hasB) v += bias[cn];
                        if (doRelu) v = fmaxf(v, 0.f);
                        C[(size_t)r * N + cn] = v;
                    }
            }
    } else {
        float* P = C + (size_t)z * M * N;
#pragma unroll
        for (int qi = 0; qi < 2; ++qi)
#pragma unroll
            for (int i = 0; i < 4; ++i) {
                const int r = bm + qi * 64 + ty * 4 + i;
                if (r >= M) continue;
#pragma unroll
                for (int qj = 0; qj < 2; ++qj)
#pragma unroll
                    for (int j = 0; j < 4; ++j) {
                        const int cn = bn + qj * 64 + tx * 4 + j;
                        P[(size_t)r * N + cn] = acc[qi][qj][i][j];
                    }
            }
    }
}

// Sum split-K partials + bias (+relu); halfOut -> write f16
__global__ __launch_bounds__(256) void reduce_partials(
    const float* __restrict__ P, const float* __restrict__ bias,
    float* __restrict__ outp, int MN, int N, int nz, int doRelu, int halfOut)
{
    const int i = blockIdx.x * 256 + threadIdx.x;
    if (i >= MN) return;
    float s = 0.f;
    for (int z = 0; z < nz; ++z) s += P[(size_t)z * MN + i];
    s += bias[i % N];
    if (doRelu) s = fmaxf(s, 0.f);
    if (halfOut) ((f16*)outp)[i] = (f16)s;
    else         outp[i] = s;
}

// w2s[k] = c2_w[k,:] . score_w   (row-dot; one block per k, coalesced)
__global__ __launch_bounds__(256) void w2s_kernel(
    const float* __restrict__ c2w, const float* __restrict__ sw,
    float* __restrict__ w2s)
{
    const int k = blockIdx.x;
    const float* rp = c2w + (size_t)k * DD;
    float s = 0.f;
    for (int n = threadIdx.x; n < DD; n += 256) s += rp[n] * sw[n];
#pragma unroll
    for (int off = 32; off >= 1; off >>= 1) s += __shfl_xor(s, off);
    __shared__ float red[4];
    if ((threadIdx.x & 63) == 0) red[threadIdx.x >> 6] = s;
    __syncthreads();
    if (threadIdx.x == 0) w2s[k] = red[0] + red[1] + red[2] + red[3];
}

// scores[row] = hidden[row,:] . w2s   (constant offset dropped: rank-invariant)
__global__ __launch_bounds__(256) void score2_kernel(
    const float* __restrict__ hidden, const float* __restrict__ w2s,
    float* __restrict__ scores)
{
    const int row = blockIdx.x;
    const float* hp = hidden + (size_t)row * DD;
    float s = 0.f;
    for (int k = threadIdx.x; k < DD; k += 256) s += hp[k] * w2s[k];
#pragma unroll
    for (int off = 32; off >= 1; off >>= 1) s += __shfl_xor(s, off);
    __shared__ float red[4];
    if ((threadIdx.x & 63) == 0) red[threadIdx.x >> 6] = s;
    __syncthreads();
    if (threadIdx.x == 0) scores[row] = red[0] + red[1] + red[2] + red[3];
}

// top-16 of 127 scores per batch (set semantics; lowest-index tie-break)
__global__ __launch_bounds__(128) void topk_kernel(
    const float* __restrict__ scores, int* __restrict__ top)
{
    const int b = blockIdx.x;
    const int t = threadIdx.x;  // 128
    __shared__ float sval[128];
    __shared__ float sv2[128];
    __shared__ int   si2[128];
    __shared__ unsigned char used[128];
    sval[t] = (t < NBLK) ? scores[b * NBLK + t] : -INFINITY;
    used[t] = 0;
    __syncthreads();
    for (int j = 0; j < NSEL; ++j) {
        sv2[t] = used[t] ? -INFINITY : sval[t];
        si2[t] = t;
        __syncthreads();
        for (int stp = 64; stp >= 1; stp >>= 1) {
            if (t < stp) {
                if (sv2[t + stp] > sv2[t] ||
                    (sv2[t + stp] == sv2[t] && si2[t + stp] < si2[t])) {
                    sv2[t] = sv2[t + stp];
                    si2[t] = si2[t + stp];
                }
            }
            __syncthreads();
        }
        if (t == 0) { top[b * NSEL + j] = si2[0]; used[si2[0]] = 1; }
        __syncthreads();
    }
}

// ---------------------------------------------------------------------------
// Attention (MFMA, f16 I/O): block = 4 waves, one (b,h,64-query tile).
// ---------------------------------------------------------------------------
#define QT 64
#define KROWS 96   // QT + 2*WIN
#define KST2 72    // K/sK row stride in halves (144 B)
#define VST 136    // Vt row stride in halves
#define PST 136    // P row stride in halves

__global__ __launch_bounds__(256) void attn_mfma(
    const f16* __restrict__ qkv, const f16* __restrict__ sqkv,
    f16* __restrict__ attn)
{
    __shared__ f16 Kl[KROWS][KST2];      // 13824 B
    __shared__ f16 sKl[NSEL][KST2];      //  2304 B
    __shared__ f16 Vt[DH][VST];          // 17408 B  (cols: 0..95 win, 96..111 sel, 112..127 zero)
    __shared__ f16 Pl[4][16][PST];       // 17408 B  per-wave P[q16][kv128]

    int bid = blockIdx.x;
    bid = (bid & 7) * (gridDim.x >> 3) + (bid >> 3);   // XCD swizzle (1024%8==0)
    const int t = bid & 31;
    const int h = (bid >> 5) & (HH - 1);
    const int b = bid >> 9;
    const int s0 = t * QT;

    const int tid = threadIdx.x;
    const int wid = tid >> 6, lane = tid & 63;
    const int l15 = lane & 15, lg = lane >> 4;

    // ---- stage K rows + V transposed ----
    for (int i = tid; i < KROWS * 8; i += 256) {
        const int row = i >> 3, c8 = (i & 7) * 8;
        const int pos = s0 - WIN + row;
        f16x8 kv, vv;
#pragma unroll
        for (int u = 0; u < 8; ++u) { kv[u] = (f16)0.f; vv[u] = (f16)0.f; }
        if (pos >= 0 && pos < SS) {
            const f16* base = qkv + (size_t)(b * SS + pos) * (3 * DD) + h * DH + c8;
            kv = *(const f16x8*)(base + DD);
            vv = *(const f16x8*)(base + 2 * DD);
        }
        *(f16x8*)&Kl[row][c8] = kv;
#pragma unroll
        for (int u = 0; u < 8; ++u) Vt[c8 + u][row] = vv[u];
    }
    // ---- stage sel K/V ----
    if (tid < NSEL * 8) {
        const int si = tid >> 3, c8 = (tid & 7) * 8;
        const f16* base = sqkv + (size_t)(b * NSEL + si) * (3 * DD) + h * DH + c8;
        f16x8 kv = *(const f16x8*)(base + DD);
        f16x8 vv = *(const f16x8*)(base + 2 * DD);
        *(f16x8*)&sKl[si][c8] = kv;
#pragma unroll
        for (int u = 0; u < 8; ++u) Vt[c8 + u][96 + si] = vv[u];
    }
    // ---- zero Vt kv columns 112..127 ----
    for (int i = tid; i < DH * 16; i += 256)
        Vt[i >> 4][112 + (i & 15)] = (f16)0.f;

    // ---- Q fragments: raw f16x8 loads ----
    f16x8 qf[2];
    {
        const f16* qp = qkv + (size_t)(b * SS + s0 + wid * 16 + l15) * (3 * DD)
                      + h * DH + lg * 8;
        qf[0] = *(const f16x8*)(qp);
        qf[1] = *(const f16x8*)(qp + 32);
    }
    __syncthreads();

    // ---- QK^T swapped: D[kv][q] ----
    f32x4 aqk[6], asel;
#pragma unroll
    for (int i = 0; i < 6; ++i) aqk[i] = (f32x4){0.f, 0.f, 0.f, 0.f};
    asel = (f32x4){0.f, 0.f, 0.f, 0.f};
#pragma unroll
    for (int kc = 0; kc < 2; ++kc) {
        const int ko = kc * 32 + lg * 8;
#pragma unroll
        for (int kvb = 0; kvb < 6; ++kvb) {
            f16x8 ka = *(const f16x8*)&Kl[kvb * 16 + l15][ko];
            aqk[kvb] = __builtin_amdgcn_mfma_f32_16x16x32_f16(ka, qf[kc], aqk[kvb], 0, 0, 0);
        }
        f16x8 ks = *(const f16x8*)&sKl[l15][ko];
        asel = __builtin_amdgcn_mfma_f32_16x16x32_f16(ks, qf[kc], asel, 0, 0, 0);
    }

    // ---- local softmax ----
    const int qt_ = wid * 16 + l15;
    float sc[6][4];
    float m = -INFINITY;
#pragma unroll
    for (int kvb = 0; kvb < 6; ++kvb)
#pragma unroll
        for (int r = 0; r < 4; ++r) {
            const int kv  = kvb * 16 + lg * 4 + r;
            const int pos = s0 - WIN + kv;
            const int dlt = kv - qt_;
            const bool ok = (dlt >= 0) & (dlt <= 32) & (pos >= 0) & (pos < SS);
            sc[kvb][r] = ok ? aqk[kvb][r] * SCALE : -INFINITY;
            m = fmaxf(m, sc[kvb][r]);
        }
    m = fmaxf(m, __shfl_xor(m, 16));
    m = fmaxf(m, __shfl_xor(m, 32));
    float sum = 0.f;
#pragma unroll
    for (int kvb = 0; kvb < 6; ++kvb)
#pragma unroll
        for (int r = 0; r < 4; ++r) {
            sc[kvb][r] = __expf(sc[kvb][r] - m);
            sum += sc[kvb][r];
        }
    sum += __shfl_xor(sum, 16);
    sum += __shfl_xor(sum, 32);
    const float inv1 = 1.f / sum;

    // ---- sel softmax ----
    float s2[4];
    float m2 = -INFINITY;
#pragma unroll
    for (int r = 0; r < 4; ++r) { s2[r] = asel[r] * SCALE; m2 = fmaxf(m2, s2[r]); }
    m2 = fmaxf(m2, __shfl_xor(m2, 16));
    m2 = fmaxf(m2, __shfl_xor(m2, 32));
    float sum2 = 0.f;
#pragma unroll
    for (int r = 0; r < 4; ++r) { s2[r] = __expf(s2[r] - m2); sum2 += s2[r]; }
    sum2 += __shfl_xor(sum2, 16);
    sum2 += __shfl_xor(sum2, 32);
    const float inv2 = 1.f / sum2;

    // ---- write P (pre-normalized); Pl is wave-private -> no barrier ----
#pragma unroll
    for (int kvb = 0; kvb < 6; ++kvb) {
        h2 p01, p23;
        p01[0] = (f16)(sc[kvb][0] * inv1); p01[1] = (f16)(sc[kvb][1] * inv1);
        p23[0] = (f16)(sc[kvb][2] * inv1); p23[1] = (f16)(sc[kvb][3] * inv1);
        *(h2*)&Pl[wid][l15][kvb * 16 + lg * 4]     = p01;
        *(h2*)&Pl[wid][l15][kvb * 16 + lg * 4 + 2] = p23;
    }
    {
        h2 g01, g23, z0;
        g01[0] = (f16)(s2[0] * inv2); g01[1] = (f16)(s2[1] * inv2);
        g23[0] = (f16)(s2[2] * inv2); g23[1] = (f16)(s2[3] * inv2);
        z0[0] = (f16)0.f; z0[1] = (f16)0.f;
        *(h2*)&Pl[wid][l15][96 + lg * 4]      = g01;
        *(h2*)&Pl[wid][l15][96 + lg * 4 + 2]  = g23;
        *(h2*)&Pl[wid][l15][112 + lg * 4]     = z0;
        *(h2*)&Pl[wid][l15][112 + lg * 4 + 2] = z0;
    }

    // ---- PV: O[q][d] = P[q][kv] . Vt[d][kv] ----
    f32x4 ov[4];
#pragma unroll
    for (int i = 0; i < 4; ++i) ov[i] = (f32x4){0.f, 0.f, 0.f, 0.f};
#pragma unroll
    for (int kc = 0; kc < 4; ++kc) {
        const int ko = kc * 32 + lg * 8;
        f16x8 pa = *(const f16x8*)&Pl[wid][l15][ko];
#pragma unroll
        for (int db = 0; db < 4; ++db) {
            f16x8 vb = *(const f16x8*)&Vt[db * 16 + l15][ko];
            ov[db] = __builtin_amdgcn_mfma_f32_16x16x32_f16(pa, vb, ov[db], 0, 0, 0);
        }
    }

    // ---- store O ----
    const size_t rbase = (size_t)(b * SS + s0 + wid * 16 + lg * 4);
#pragma unroll
    for (int r = 0; r < 4; ++r) {
        f16* op = attn + (rbase + r) * DD + h * DH + l15;
#pragma unroll
        for (int db = 0; db < 4; ++db)
            op[db * 16] = (f16)ov[db][r];
    }
}

extern "C" void kernel_launch(void* const* d_in, const int* in_sizes, int n_in,
                              void* d_out, int out_size, void* d_ws, size_t ws_size,
                              hipStream_t stream)
{
    const float* x       = (const float*)d_in[0];
    const float* qkv_w   = (const float*)d_in[1];
    const float* qkv_b   = (const float*)d_in[2];
    const float* c1_w    = (const float*)d_in[3];
    const float* c1_b    = (const float*)d_in[4];
    const float* c2_w    = (const float*)d_in[5];
    const float* c2_b    = (const float*)d_in[6];
    const float* score_w = (const float*)d_in[7];
    const float* score_b = (const float*)d_in[8];
    const float* out_w   = (const float*)d_in[9];
    const float* out_b   = (const float*)d_in[10];
    float* out = (float*)d_out;
    float* ws  = (float*)d_ws;
    (void)score_b;   // rank-invariant constant (c2_b.score_w + score_b) dropped

    // workspace layout (float units); fill evidence shows ws >= 134M floats
    f16*   xh      = (f16*)ws;                   // 4096x1024 halves
    float* A1      = ws + 2097152;
    f16*   qkvb    = (f16*)A1;                   // 4096x3072 halves
    f16*   attnf   = (f16*)(A1 + 12582912);      // 4096x1024 halves
    float* A2      = ws + 18874368;              // small split-K partials
    float* part    = A2;
    float* hidden  = ws + 23035904;              // 260,096
    float* scores  = hidden + 260096;            // 256
    int*   topIdx  = (int*)(scores + 256);       // 32 ints
    float* sqkvb   = scores + 256 + 64;          // f16 region, 49,152 floats
    float* w2s     = sqkvb + 49152;              // 1024
    float* compSel = w2s + 1024;                 // 32 x 1024 fp32
    float* partC1  = ws + 24000000;              // 32 x 254 x 1024 = 8.3M floats
    f16*   qkv_wT  = (f16*)(ws + 33000000);      // 3072x1024 halves (fresh)
    f16*   out_wT  = (f16*)(ws + 34600000);      // 1024x1024 halves (fresh)

    const int MROWS = BB * SS;        // 4096
    const int MSEL  = BB * NSEL;      // 32

    // 0. x -> f16
    convert_f16<<<(MROWS * DD) / (256 * 4), 256, 0, stream>>>(x, xh, MROWS * DD);

    // 1. c1: hidden partials via f16 MFMA (fused B transpose), split-K 32
    //    -> 1024 blocks = 4 blocks/CU (residency doubled vs R9)
    gemm_c1<<<dim3(DD / 64, 2, C1_NZ), 256, 0, stream>>>(xh, c1_w, partC1);

    // 2. hidden = relu(sum partials + c1_b)  [fp32]
    reduce_partials<<<(MC * DD) / 256, 256, 0, stream>>>(
        partC1, c1_b, hidden, MC * DD, DD, C1_NZ, 1, 0);

    // 3. w2s = c2_w @ score_w  (row-dots)
    w2s_kernel<<<DD, 256, 0, stream>>>(c2_w, score_w, w2s);

    // 4. scores = hidden @ w2s  (constant offset dropped; rank-invariant)
    score2_kernel<<<MC, 256, 0, stream>>>(hidden, w2s, scores);

    // 5. top-16 per batch
    topk_kernel<<<BB, 128, 0, stream>>>(scores, topIdx);

    // 6. compSel partials: hidden[sel] @ c2_w  (32 x 1024, K=1024, split-K 16)
    gemm128<2><<<dim3(DD / 128, 1, 16), 256, 0, stream>>>(
        hidden, c2_w, nullptr, part, MSEL, DD, DD, topIdx, 0);

    // 6b. compSel = sum partials + c2_b  [fp32]
    reduce_partials<<<(MSEL * DD) / 256, 256, 0, stream>>>(
        part, c2_b, compSel, MSEL * DD, DD, 16, 0, 0);

    // 7. sqkv partials: compSel @ qkv_w  (32 x 3072, K=1024, split-K 16)
    gemm128<0><<<dim3(3 * DD / 128, 1, 16), 256, 0, stream>>>(
        compSel, qkv_w, nullptr, part, MSEL, 3 * DD, DD, nullptr, 0);

    // 7b. sqkv = sum partials + qkv_b  [f16]
    reduce_partials<<<(MSEL * 3 * DD + 255) / 256, 256, 0, stream>>>(
        part, qkv_b, sqkvb, MSEL * 3 * DD, 3 * DD, 16, 0, 1);

    // 8. weight transposes (fresh regions)
    transpose_conv<<<dim3(3 * DD / 32, DD / 32), 256, 0, stream>>>(
        qkv_w, qkv_wT, DD, 3 * DD);
    transpose_conv<<<dim3(DD / 32, DD / 32), 256, 0, stream>>>(
        out_w, out_wT, DD, DD);

    // 9. qkv = x @ qkv_w + qkv_b  [f16 MFMA, f16 out]
    gemm_f16<1><<<dim3(3 * DD / 128, MROWS / 128), 256, 0, stream>>>(
        xh, qkv_wT, qkv_b, (float*)qkvb, MROWS, 3 * DD, DD);

    // 10. attention on matrix cores (f16 I/O)
    attn_mfma<<<BB * HH * (SS / QT), 256, 0, stream>>>(
        qkvb, (const f16*)sqkvb, attnf);

    // 11. out = attn @ out_w + out_b  [f16 MFMA, fp32 out]
    gemm_f16<0><<<dim3(DD / 128, MROWS / 128), 256, 0, stream>>>(
        attnf, out_wT, out_b, out, MROWS, DD, DD);
}

// Round 16
// 219.419 us; speedup vs baseline: 1.1553x; 1.0370x over previous
//
#include <hip/hip_runtime.h>
#include <math.h>

// Problem constants
#define BB   2
#define SS   2048
#define DD   1024
#define HH   16
#define DH   64
#define CBS  32
#define STRIDEC 16
#define NBLK 127          // (S - CBS)/STRIDE + 1
#define NSEL 16
#define WIN  16
#define NW   33           // 2*WIN+1
#define SCALE 0.125f      // DH^-0.5
#define MC   254          // BB * NBLK

typedef _Float16 f16;
typedef __attribute__((ext_vector_type(8))) _Float16 f16x8;
typedef __attribute__((ext_vector_type(4))) _Float16 f16x4;
typedef __attribute__((ext_vector_type(2))) _Float16 h2;
typedef __attribute__((ext_vector_type(4))) float f32x4;

// ---------------------------------------------------------------------------
// fp32 -> f16 elementwise convert (float4 loads, 4 elems/thread)
// ---------------------------------------------------------------------------
__global__ __launch_bounds__(256) void convert_f16(
    const float* __restrict__ src, f16* __restrict__ dst, int n)
{
    const int i = (blockIdx.x * 256 + threadIdx.x) * 4;
    if (i >= n) return;
    float4 v = *(const float4*)(src + i);
    f16x4 o;
    o[0] = (f16)v.x; o[1] = (f16)v.y; o[2] = (f16)v.z; o[3] = (f16)v.w;
    *(f16x4*)(dst + i) = o;
}

// ---------------------------------------------------------------------------
// fp32 (K x N) -> f16 (N x K) transpose-convert, 32x32 LDS tiles
// ---------------------------------------------------------------------------
__global__ __launch_bounds__(256) void transpose_conv(
    const float* __restrict__ src, f16* __restrict__ dst, int K, int N)
{
    __shared__ float t[32][33];
    const int n0 = blockIdx.x * 32, k0 = blockIdx.y * 32;
    const int tx = threadIdx.x & 31, ty = threadIdx.x >> 5;   // 32 x 8
#pragma unroll
    for (int r = 0; r < 32; r += 8)
        t[ty + r][tx] = src[(size_t)(k0 + ty + r) * N + n0 + tx];
    __syncthreads();
#pragma unroll
    for (int r = 0; r < 32; r += 8)
        dst[(size_t)(n0 + ty + r) * K + k0 + tx] = (f16)t[tx][ty + r];
}

// ---------------------------------------------------------------------------
// f16 MFMA GEMM, m97-style: 128x128 tile, BK=64, 4 waves (2x2).  XCD-aware
// block swizzle RESTORED (R9 config; ledger decomposition shows removing it
// cost ~+4 us — qkv B-panels live in the 4 MB per-XCD L2, not L3).
// Grid totals 768 / 256, both % 8 == 0 -> bijective.
// ---------------------------------------------------------------------------
template<int OUT16>
__global__ __launch_bounds__(256) void gemm_f16(
    const f16* __restrict__ A, const f16* __restrict__ Bt,
    const float* __restrict__ bias, float* __restrict__ C,
    int M, int N, int K)
{
    constexpr int BK = 64;
    __shared__ f16 As[128 * BK];
    __shared__ f16 Bs[128 * BK];
    const int tid  = threadIdx.x;
    const int wid  = tid >> 6, lane = tid & 63;

    int lin = blockIdx.y * gridDim.x + blockIdx.x;
    const int nb = gridDim.x * gridDim.y;
    lin = (lin & 7) * (nb >> 3) + (lin >> 3);
    const int bx = lin % gridDim.x, by = lin / gridDim.x;

    const int bm = by * 128, bn = bx * 128;
    const int wm = (wid >> 1) * 64, wn = (wid & 1) * 64;

    const int lrow = lane >> 3;        // 0..7 (row within 8-row segment)
    const int lk8  = (lane & 7) * 8;   // k-element offset of this lane's 16B

    f32x4 acc[4][4];
#pragma unroll
    for (int i = 0; i < 4; ++i)
#pragma unroll
        for (int j = 0; j < 4; ++j) acc[i][j] = (f32x4){0.f, 0.f, 0.f, 0.f};

    for (int kt = 0; kt < K; kt += BK) {
#pragma unroll
        for (int c = 0; c < 4; ++c) {
            const int seg = c * 4 + wid;            // 0..15 -> rows seg*8..+8
            const int row = seg * 8 + lrow;
            const f16* ga = A + (size_t)(bm + row) * K + kt + lk8;
            __builtin_amdgcn_global_load_lds(
                (const __attribute__((address_space(1))) void*)(const void*)ga,
                (__attribute__((address_space(3))) void*)(void*)(As + seg * 512),
                16, 0, 0);
            const f16* gb = Bt + (size_t)(bn + row) * K + kt + lk8;
            __builtin_amdgcn_global_load_lds(
                (const __attribute__((address_space(1))) void*)(const void*)gb,
                (__attribute__((address_space(3))) void*)(void*)(Bs + seg * 512),
                16, 0, 0);
        }
        __syncthreads();   // compiler drains vmcnt before s_barrier

#pragma unroll
        for (int kk = 0; kk < 2; ++kk) {
            const int ko = kk * 32 + (lane >> 4) * 8;
            f16x8 a[4], b[4];
#pragma unroll
            for (int i = 0; i < 4; ++i)
                a[i] = *(const f16x8*)(As + (wm + i * 16 + (lane & 15)) * BK + ko);
#pragma unroll
            for (int j = 0; j < 4; ++j)
                b[j] = *(const f16x8*)(Bs + (wn + j * 16 + (lane & 15)) * BK + ko);
#pragma unroll
            for (int i = 0; i < 4; ++i)
#pragma unroll
                for (int j = 0; j < 4; ++j)
                    acc[i][j] = __builtin_amdgcn_mfma_f32_16x16x32_f16(
                        a[i], b[j], acc[i][j], 0, 0, 0);
        }
        __syncthreads();
    }

    const int rr0 = (lane >> 4) * 4;
    const int cc  = lane & 15;
#pragma unroll
    for (int i = 0; i < 4; ++i) {
        const int r = bm + wm + i * 16 + rr0;
#pragma unroll
        for (int j = 0; j < 4; ++j) {
            const int cn = bn + wn + j * 16 + cc;
            const float bv = bias[cn];
#pragma unroll
            for (int q = 0; q < 4; ++q) {
                if constexpr (OUT16)
                    ((f16*)C)[(size_t)(r + q) * N + cn] = (f16)(acc[i][j][q] + bv);
                else
                    C[(size_t)(r + q) * N + cn] = acc[i][j][q] + bv;
            }
        }
    }
}

// ---------------------------------------------------------------------------
// c1 compression GEMM — R9's fused version + T14 async-STAGE split on the
// B path: B register-loads for tile t+1 are issued BEFORE MFMA(t), so their
// cold-HBM latency hides under compute instead of being serially exposed at
// the stage->drain->barrier path (the invariant cost across R10-R15).
// MFMA sequence / write order / indexing bit-identical to R9.
// Grid (16, 2, 16) = 512 blocks, split-K 16.
// ---------------------------------------------------------------------------
#define C1_NZ 16
#define C1_KCHUNK 2048     // 32768 / 16

__global__ __launch_bounds__(256) void gemm_c1(
    const f16* __restrict__ xh, const float* __restrict__ c1w,
    float* __restrict__ P)
{
    constexpr int BK = 64;
    constexpr int BSTR = 72;          // halves (144 B rows)
    __shared__ f16 As[128 * BK];      // 16 KB
    __shared__ f16 Bs[64 * BSTR];     // 9216 B
    const int tid  = threadIdx.x;
    const int wid  = tid >> 6, lane = tid & 63;
    const int bn = blockIdx.x * 64, bm = blockIdx.y * 128;
    const int z  = blockIdx.z;
    const int wm = (wid >> 1) * 64, wn = (wid & 1) * 32;

    const int lrow = lane >> 3;
    const int lk8  = (lane & 7) * 8;

    const int kk0 = (tid >> 4) * 2;   // 0..30 even
    const int n4  = (tid & 15) * 4;

    f32x4 acc[4][2];
#pragma unroll
    for (int i = 0; i < 4; ++i)
#pragma unroll
        for (int j = 0; j < 2; ++j) acc[i][j] = (f32x4){0.f, 0.f, 0.f, 0.f};

    auto loadB = [&](int t, float4& r00, float4& r01, float4& r10, float4& r11) {
        const int ktg = z * C1_KCHUNK + t * BK;
        const float* gB0 = c1w + (size_t)(ktg + kk0) * DD + bn + n4;
        const float* gB1 = c1w + (size_t)(ktg + kk0 + 32) * DD + bn + n4;
        r00 = *(const float4*)gB0;
        r01 = *(const float4*)(gB0 + DD);
        r10 = *(const float4*)gB1;
        r11 = *(const float4*)(gB1 + DD);
    };
    auto writeB = [&](float4 r00, float4 r01, float4 r10, float4 r11) {
        // identical store pattern/order to R9 (p=0 then p=1)
        {
            const int kk = kk0;
            const float a0[4] = {r00.x, r00.y, r00.z, r00.w};
            const float a1[4] = {r01.x, r01.y, r01.z, r01.w};
#pragma unroll
            for (int u = 0; u < 4; ++u) {
                const int n = n4 + u;
                h2 w; w[0] = (f16)a0[u]; w[1] = (f16)a1[u];
                *(h2*)&Bs[n * BSTR + (kk ^ (((n >> 3) & 3) << 3))] = w;
            }
        }
        {
            const int kk = kk0 + 32;
            const float a0[4] = {r10.x, r10.y, r10.z, r10.w};
            const float a1[4] = {r11.x, r11.y, r11.z, r11.w};
#pragma unroll
            for (int u = 0; u < 4; ++u) {
                const int n = n4 + u;
                h2 w; w[0] = (f16)a0[u]; w[1] = (f16)a1[u];
                *(h2*)&Bs[n * BSTR + (kk ^ (((n >> 3) & 3) << 3))] = w;
            }
        }
    };

    // prologue: B(0) into regs
    float4 b00, b01, b10, b11;
    loadB(0, b00, b01, b10, b11);

    for (int t = 0; t < C1_KCHUNK / BK; ++t) {   // 32 iterations
        const int ktg = z * C1_KCHUNK + t * BK;
        const int kc  = (ktg + lk8) >> 10;       // x feature-row within block
        const int kd  = (ktg + lk8) & 1023;      // x col

        // write B(t) from regs (prev barrier ensured Bs readers done)
        writeB(b00, b01, b10, b11);
        // stage A(t) via global_load_lds
#pragma unroll
        for (int c = 0; c < 4; ++c) {
            const int seg = c * 4 + wid;
            int row = bm + seg * 8 + lrow;
            if (row > MC - 1) row = MC - 1;       // pad rows 254/255 (dup, unstored)
            const int b   = (row >= NBLK) ? 1 : 0;
            const int blk = row - b * NBLK;
            const f16* ga = xh + ((size_t)(b * SS + blk * STRIDEC + kc) << 10) + kd;
            __builtin_amdgcn_global_load_lds(
                (const __attribute__((address_space(1))) void*)(const void*)ga,
                (__attribute__((address_space(3))) void*)(void*)(As + seg * 512),
                16, 0, 0);
        }
        // T14: issue B(t+1) loads now — latency hides under barrier + MFMA(t)
        if (t + 1 < C1_KCHUNK / BK)
            loadB(t + 1, b00, b01, b10, b11);

        __syncthreads();

#pragma unroll
        for (int kk = 0; kk < 2; ++kk) {
            const int ko = kk * 32 + (lane >> 4) * 8;
            f16x8 a[4], b[2];
#pragma unroll
            for (int i = 0; i < 4; ++i)
                a[i] = *(const f16x8*)(As + (wm + i * 16 + (lane & 15)) * BK + ko);
#pragma unroll
            for (int j = 0; j < 2; ++j) {
                const int n = wn + j * 16 + (lane & 15);
                b[j] = *(const f16x8*)&Bs[n * BSTR + (ko ^ (((n >> 3) & 3) << 3))];
            }
#pragma unroll
            for (int i = 0; i < 4; ++i)
#pragma unroll
                for (int j = 0; j < 2; ++j)
                    acc[i][j] = __builtin_amdgcn_mfma_f32_16x16x32_f16(
                        a[i], b[j], acc[i][j], 0, 0, 0);
        }
        __syncthreads();
    }

    const int rr0 = (lane >> 4) * 4;
    const int cc  = lane & 15;
#pragma unroll
    for (int i = 0; i < 4; ++i) {
        const int r = bm + wm + i * 16 + rr0;
#pragma unroll
        for (int j = 0; j < 2; ++j) {
            const int cn = bn + wn + j * 16 + cc;
#pragma unroll
            for (int q = 0; q < 4; ++q)
                if (r + q < MC)
                    P[((size_t)z * MC + r + q) * DD + cn] = acc[i][j][q];
        }
    }
}

// ---------------------------------------------------------------------------
// fp32 tiled GEMM 128x128 — small fp32-exact kernels: compSel (MODE 2,
// gather rows of `hidden` by topIdx) and sqkv (MODE 0), split-K partials.
// ---------------------------------------------------------------------------
template<int MODE>
__global__ __launch_bounds__(256) void gemm128(
    const float* __restrict__ A, const float* __restrict__ Bm,
    const float* __restrict__ bias, float* __restrict__ C,
    int M, int N, int K, const int* __restrict__ selIdx, int flags)
{
    __shared__ float As[8][132];
    __shared__ float Bs[8][132];

    const int tid = threadIdx.x;
    const int bm = blockIdx.y * 128;
    const int bn = blockIdx.x * 128;
    const int nz = gridDim.z;
    const int z  = blockIdx.z;
    const int kchunk = K / nz;
    const int k0 = z * kchunk;
    const int kend = k0 + kchunk;

    const int tx = tid & 15;
    const int ty = tid >> 4;

    const int arow = tid >> 1;
    const int akq  = (tid & 1) * 4;
    const int bkr  = tid >> 5;
    const int bcol = (tid & 31) * 4;

    float acc[2][2][4][4];
#pragma unroll
    for (int qi = 0; qi < 2; ++qi)
#pragma unroll
        for (int qj = 0; qj < 2; ++qj)
#pragma unroll
            for (int i = 0; i < 4; ++i)
#pragma unroll
                for (int j = 0; j < 4; ++j) acc[qi][qj][i][j] = 0.f;

    auto loadA = [&](int kt) -> float4 {
        float4 av = make_float4(0.f, 0.f, 0.f, 0.f);
        const int grow = bm + arow;
        if (grow < M) {
            if constexpr (MODE == 0) {
                av = *(const float4*)(A + (size_t)grow * K + kt + akq);
            } else {
                const int b = grow >> 4;
                const int j = grow & 15;
                const int idx = selIdx[b * NSEL + j];
                av = *(const float4*)(A + (size_t)(b * NBLK + idx) * K + kt + akq);
            }
        }
        return av;
    };
    auto loadB = [&](int kt) -> float4 {
        return *(const float4*)(Bm + (size_t)(kt + bkr) * N + bn + bcol);
    };

    float4 av = loadA(k0);
    float4 bv = loadB(k0);

    for (int kt = k0; kt < kend; kt += 8) {
        As[akq + 0][arow] = av.x;
        As[akq + 1][arow] = av.y;
        As[akq + 2][arow] = av.z;
        As[akq + 3][arow] = av.w;
        *(float4*)&Bs[bkr][bcol] = bv;
        __syncthreads();
        if (kt + 8 < kend) {
            av = loadA(kt + 8);
            bv = loadB(kt + 8);
        }
#pragma unroll
        for (int k = 0; k < 8; ++k) {
            const float4 a0 = *(const float4*)&As[k][ty * 4];
            const float4 a1 = *(const float4*)&As[k][64 + ty * 4];
            const float4 b0 = *(const float4*)&Bs[k][tx * 4];
            const float4 b1 = *(const float4*)&Bs[k][64 + tx * 4];
            const float ar[2][4] = {{a0.x, a0.y, a0.z, a0.w},
                                    {a1.x, a1.y, a1.z, a1.w}};
            const float br[2][4] = {{b0.x, b0.y, b0.z, b0.w},
                                    {b1.x, b1.y, b1.z, b1.w}};
#pragma unroll
            for (int qi = 0; qi < 2; ++qi)
#pragma unroll
                for (int i = 0; i < 4; ++i)
#pragma unroll
                    for (int qj = 0; qj < 2; ++qj)
#pragma unroll
                        for (int j = 0; j < 4; ++j)
                            acc[qi][qj][i][j] += ar[qi][i] * br[qj][j];
        }
        __syncthreads();
    }

    if (nz == 1) {
        const bool hasB   = (flags & 1) != 0;
        const bool doRelu = (flags & 2) != 0;
#pragma unroll
        for (int qi = 0; qi < 2; ++qi)
#pragma unroll
            for (int i = 0; i < 4; ++i) {
                const int r = bm + qi * 64 + ty * 4 + i;
                if (r >= M) continue;
#pragma unroll
                for (int qj = 0; qj < 2; ++qj)
#pragma unroll
                    for (int j = 0; j < 4; ++j) {
                        const int cn = bn + qj * 64 + tx * 4 + j;
                        float v = acc[qi][qj][i][j];
                        if (hasB) v += bias[cn];
                        if (doRelu) v = fmaxf(v, 0.f);
                        C[(size_t)r * N + cn] = v;
                    }
            }
    } else {
        float* P = C + (size_t)z * M * N;
#pragma unroll
        for (int qi = 0; qi < 2; ++qi)
#pragma unroll
            for (int i = 0; i < 4; ++i) {
                const int r = bm + qi * 64 + ty * 4 + i;
                if (r >= M) continue;
#pragma unroll
                for (int qj = 0; qj < 2; ++qj)
#pragma unroll
                    for (int j = 0; j < 4; ++j) {
                        const int cn = bn + qj * 64 + tx * 4 + j;
                        P[(size_t)r * N + cn] = acc[qi][qj][i][j];
                    }
            }
    }
}

// Sum split-K partials + bias (+relu); halfOut -> write f16
__global__ __launch_bounds__(256) void reduce_partials(
    const float* __restrict__ P, const float* __restrict__ bias,
    float* __restrict__ outp, int MN, int N, int nz, int doRelu, int halfOut)
{
    const int i = blockIdx.x * 256 + threadIdx.x;
    if (i >= MN) return;
    float s = 0.f;
    for (int z = 0; z < nz; ++z) s += P[(size_t)z * MN + i];
    s += bias[i % N];
    if (doRelu) s = fmaxf(s, 0.f);
    if (halfOut) ((f16*)outp)[i] = (f16)s;
    else         outp[i] = s;
}

// w2s[k] = c2_w[k,:] . score_w   (row-dot; one block per k, coalesced)
__global__ __launch_bounds__(256) void w2s_kernel(
    const float* __restrict__ c2w, const float* __restrict__ sw,
    float* __restrict__ w2s)
{
    const int k = blockIdx.x;
    const float* rp = c2w + (size_t)k * DD;
    float s = 0.f;
    for (int n = threadIdx.x; n < DD; n += 256) s += rp[n] * sw[n];
#pragma unroll
    for (int off = 32; off >= 1; off >>= 1) s += __shfl_xor(s, off);
    __shared__ float red[4];
    if ((threadIdx.x & 63) == 0) red[threadIdx.x >> 6] = s;
    __syncthreads();
    if (threadIdx.x == 0) w2s[k] = red[0] + red[1] + red[2] + red[3];
}

// scores[row] = hidden[row,:] . w2s   (constant offset dropped: rank-invariant)
__global__ __launch_bounds__(256) void score2_kernel(
    const float* __restrict__ hidden, const float* __restrict__ w2s,
    float* __restrict__ scores)
{
    const int row = blockIdx.x;
    const float* hp = hidden + (size_t)row * DD;
    float s = 0.f;
    for (int k = threadIdx.x; k < DD; k += 256) s += hp[k] * w2s[k];
#pragma unroll
    for (int off = 32; off >= 1; off >>= 1) s += __shfl_xor(s, off);
    __shared__ float red[4];
    if ((threadIdx.x & 63) == 0) red[threadIdx.x >> 6] = s;
    __syncthreads();
    if (threadIdx.x == 0) scores[row] = red[0] + red[1] + red[2] + red[3];
}

// top-16 of 127 scores per batch (set semantics; lowest-index tie-break)
__global__ __launch_bounds__(128) void topk_kernel(
    const float* __restrict__ scores, int* __restrict__ top)
{
    const int b = blockIdx.x;
    const int t = threadIdx.x;  // 128
    __shared__ float sval[128];
    __shared__ float sv2[128];
    __shared__ int   si2[128];
    __shared__ unsigned char used[128];
    sval[t] = (t < NBLK) ? scores[b * NBLK + t] : -INFINITY;
    used[t] = 0;
    __syncthreads();
    for (int j = 0; j < NSEL; ++j) {
        sv2[t] = used[t] ? -INFINITY : sval[t];
        si2[t] = t;
        __syncthreads();
        for (int stp = 64; stp >= 1; stp >>= 1) {
            if (t < stp) {
                if (sv2[t + stp] > sv2[t] ||
                    (sv2[t + stp] == sv2[t] && si2[t + stp] < si2[t])) {
                    sv2[t] = sv2[t + stp];
                    si2[t] = si2[t + stp];
                }
            }
            __syncthreads();
        }
        if (t == 0) { top[b * NSEL + j] = si2[0]; used[si2[0]] = 1; }
        __syncthreads();
    }
}

// ---------------------------------------------------------------------------
// Attention (MFMA, f16 I/O): block = 4 waves, one (b,h,64-query tile).
// ---------------------------------------------------------------------------
#define QT 64
#define KROWS 96   // QT + 2*WIN
#define KST2 72    // K/sK row stride in halves (144 B)
#define VST 136    // Vt row stride in halves
#define PST 136    // P row stride in halves

__global__ __launch_bounds__(256) void attn_mfma(
    const f16* __restrict__ qkv, const f16* __restrict__ sqkv,
    f16* __restrict__ attn)
{
    __shared__ f16 Kl[KROWS][KST2];      // 13824 B
    __shared__ f16 sKl[NSEL][KST2];      //  2304 B
    __shared__ f16 Vt[DH][VST];          // 17408 B  (cols: 0..95 win, 96..111 sel, 112..127 zero)
    __shared__ f16 Pl[4][16][PST];       // 17408 B  per-wave P[q16][kv128]

    int bid = blockIdx.x;
    bid = (bid & 7) * (gridDim.x >> 3) + (bid >> 3);   // XCD swizzle (1024%8==0)
    const int t = bid & 31;
    const int h = (bid >> 5) & (HH - 1);
    const int b = bid >> 9;
    const int s0 = t * QT;

    const int tid = threadIdx.x;
    const int wid = tid >> 6, lane = tid & 63;
    const int l15 = lane & 15, lg = lane >> 4;

    // ---- stage K rows + V transposed ----
    for (int i = tid; i < KROWS * 8; i += 256) {
        const int row = i >> 3, c8 = (i & 7) * 8;
        const int pos = s0 - WIN + row;
        f16x8 kv, vv;
#pragma unroll
        for (int u = 0; u < 8; ++u) { kv[u] = (f16)0.f; vv[u] = (f16)0.f; }
        if (pos >= 0 && pos < SS) {
            const f16* base = qkv + (size_t)(b * SS + pos) * (3 * DD) + h * DH + c8;
            kv = *(const f16x8*)(base + DD);
            vv = *(const f16x8*)(base + 2 * DD);
        }
        *(f16x8*)&Kl[row][c8] = kv;
#pragma unroll
        for (int u = 0; u < 8; ++u) Vt[c8 + u][row] = vv[u];
    }
    // ---- stage sel K/V ----
    if (tid < NSEL * 8) {
        const int si = tid >> 3, c8 = (tid & 7) * 8;
        const f16* base = sqkv + (size_t)(b * NSEL + si) * (3 * DD) + h * DH + c8;
        f16x8 kv = *(const f16x8*)(base + DD);
        f16x8 vv = *(const f16x8*)(base + 2 * DD);
        *(f16x8*)&sKl[si][c8] = kv;
#pragma unroll
        for (int u = 0; u < 8; ++u) Vt[c8 + u][96 + si] = vv[u];
    }
    // ---- zero Vt kv columns 112..127 ----
    for (int i = tid; i < DH * 16; i += 256)
        Vt[i >> 4][112 + (i & 15)] = (f16)0.f;

    // ---- Q fragments: raw f16x8 loads ----
    f16x8 qf[2];
    {
        const f16* qp = qkv + (size_t)(b * SS + s0 + wid * 16 + l15) * (3 * DD)
                      + h * DH + lg * 8;
        qf[0] = *(const f16x8*)(qp);
        qf[1] = *(const f16x8*)(qp + 32);
    }
    __syncthreads();

    // ---- QK^T swapped: D[kv][q] ----
    f32x4 aqk[6], asel;
#pragma unroll
    for (int i = 0; i < 6; ++i) aqk[i] = (f32x4){0.f, 0.f, 0.f, 0.f};
    asel = (f32x4){0.f, 0.f, 0.f, 0.f};
#pragma unroll
    for (int kc = 0; kc < 2; ++kc) {
        const int ko = kc * 32 + lg * 8;
#pragma unroll
        for (int kvb = 0; kvb < 6; ++kvb) {
            f16x8 ka = *(const f16x8*)&Kl[kvb * 16 + l15][ko];
            aqk[kvb] = __builtin_amdgcn_mfma_f32_16x16x32_f16(ka, qf[kc], aqk[kvb], 0, 0, 0);
        }
        f16x8 ks = *(const f16x8*)&sKl[l15][ko];
        asel = __builtin_amdgcn_mfma_f32_16x16x32_f16(ks, qf[kc], asel, 0, 0, 0);
    }

    // ---- local softmax ----
    const int qt_ = wid * 16 + l15;
    float sc[6][4];
    float m = -INFINITY;
#pragma unroll
    for (int kvb = 0; kvb < 6; ++kvb)
#pragma unroll
        for (int r = 0; r < 4; ++r) {
            const int kv  = kvb * 16 + lg * 4 + r;
            const int pos = s0 - WIN + kv;
            const int dlt = kv - qt_;
            const bool ok = (dlt >= 0) & (dlt <= 32) & (pos >= 0) & (pos < SS);
            sc[kvb][r] = ok ? aqk[kvb][r] * SCALE : -INFINITY;
            m = fmaxf(m, sc[kvb][r]);
        }
    m = fmaxf(m, __shfl_xor(m, 16));
    m = fmaxf(m, __shfl_xor(m, 32));
    float sum = 0.f;
#pragma unroll
    for (int kvb = 0; kvb < 6; ++kvb)
#pragma unroll
        for (int r = 0; r < 4; ++r) {
            sc[kvb][r] = __expf(sc[kvb][r] - m);
            sum += sc[kvb][r];
        }
    sum += __shfl_xor(sum, 16);
    sum += __shfl_xor(sum, 32);
    const float inv1 = 1.f / sum;

    // ---- sel softmax ----
    float s2[4];
    float m2 = -INFINITY;
#pragma unroll
    for (int r = 0; r < 4; ++r) { s2[r] = asel[r] * SCALE; m2 = fmaxf(m2, s2[r]); }
    m2 = fmaxf(m2, __shfl_xor(m2, 16));
    m2 = fmaxf(m2, __shfl_xor(m2, 32));
    float sum2 = 0.f;
#pragma unroll
    for (int r = 0; r < 4; ++r) { s2[r] = __expf(s2[r] - m2); sum2 += s2[r]; }
    sum2 += __shfl_xor(sum2, 16);
    sum2 += __shfl_xor(sum2, 32);
    const float inv2 = 1.f / sum2;

    // ---- write P (pre-normalized); Pl is wave-private -> no barrier ----
#pragma unroll
    for (int kvb = 0; kvb < 6; ++kvb) {
        h2 p01, p23;
        p01[0] = (f16)(sc[kvb][0] * inv1); p01[1] = (f16)(sc[kvb][1] * inv1);
        p23[0] = (f16)(sc[kvb][2] * inv1); p23[1] = (f16)(sc[kvb][3] * inv1);
        *(h2*)&Pl[wid][l15][kvb * 16 + lg * 4]     = p01;
        *(h2*)&Pl[wid][l15][kvb * 16 + lg * 4 + 2] = p23;
    }
    {
        h2 g01, g23, z0;
        g01[0] = (f16)(s2[0] * inv2); g01[1] = (f16)(s2[1] * inv2);
        g23[0] = (f16)(s2[2] * inv2); g23[1] = (f16)(s2[3] * inv2);
        z0[0] = (f16)0.f; z0[1] = (f16)0.f;
        *(h2*)&Pl[wid][l15][96 + lg * 4]      = g01;
        *(h2*)&Pl[wid][l15][96 + lg * 4 + 2]  = g23;
        *(h2*)&Pl[wid][l15][112 + lg * 4]     = z0;
        *(h2*)&Pl[wid][l15][112 + lg * 4 + 2] = z0;
    }

    // ---- PV: O[q][d] = P[q][kv] . Vt[d][kv] ----
    f32x4 ov[4];
#pragma unroll
    for (int i = 0; i < 4; ++i) ov[i] = (f32x4){0.f, 0.f, 0.f, 0.f};
#pragma unroll
    for (int kc = 0; kc < 4; ++kc) {
        const int ko = kc * 32 + lg * 8;
        f16x8 pa = *(const f16x8*)&Pl[wid][l15][ko];
#pragma unroll
        for (int db = 0; db < 4; ++db) {
            f16x8 vb = *(const f16x8*)&Vt[db * 16 + l15][ko];
            ov[db] = __builtin_amdgcn_mfma_f32_16x16x32_f16(pa, vb, ov[db], 0, 0, 0);
        }
    }

    // ---- store O ----
    const size_t rbase = (size_t)(b * SS + s0 + wid * 16 + lg * 4);
#pragma unroll
    for (int r = 0; r < 4; ++r) {
        f16* op = attn + (rbase + r) * DD + h * DH + l15;
#pragma unroll
        for (int db = 0; db < 4; ++db)
            op[db * 16] = (f16)ov[db][r];
    }
}

extern "C" void kernel_launch(void* const* d_in, const int* in_sizes, int n_in,
                              void* d_out, int out_size, void* d_ws, size_t ws_size,
                              hipStream_t stream)
{
    const float* x       = (const float*)d_in[0];
    const float* qkv_w   = (const float*)d_in[1];
    const float* qkv_b   = (const float*)d_in[2];
    const float* c1_w    = (const float*)d_in[3];
    const float* c1_b    = (const float*)d_in[4];
    const float* c2_w    = (const float*)d_in[5];
    const float* c2_b    = (const float*)d_in[6];
    const float* score_w = (const float*)d_in[7];
    const float* score_b = (const float*)d_in[8];
    const float* out_w   = (const float*)d_in[9];
    const float* out_b   = (const float*)d_in[10];
    float* out = (float*)d_out;
    float* ws  = (float*)d_ws;
    (void)score_b;   // rank-invariant constant (c2_b.score_w + score_b) dropped

    // workspace layout (float units) — R9 layout
    f16*   xh      = (f16*)ws;                   // 4096x1024 halves
    float* A1      = ws + 2097152;
    f16*   qkvb    = (f16*)A1;                   // 4096x3072 halves
    f16*   attnf   = (f16*)(A1 + 12582912);      // 4096x1024 halves
    float* A2      = ws + 18874368;              // 4,161,536 floats scratch
    float* part    = A2;
    f16*   qkv_wT  = (f16*)A2;                   // alias (partials dead first)
    f16*   out_wT  = (f16*)(A2 + 1572864);
    float* hidden  = ws + 23035904;              // 260,096
    float* scores  = hidden + 260096;            // 256
    int*   topIdx  = (int*)(scores + 256);       // 32 ints
    float* sqkvb   = scores + 256 + 64;          // f16 region, 49,152 floats
    float* w2s     = sqkvb + 49152;              // 1024
    float* compSel = w2s + 1024;                 // 32 x 1024 fp32

    const int MROWS = BB * SS;        // 4096
    const int MSEL  = BB * NSEL;      // 32

    // 0. x -> f16
    convert_f16<<<(MROWS * DD) / (256 * 4), 256, 0, stream>>>(x, xh, MROWS * DD);

    // 1. c1: hidden partials via f16 MFMA (fused B transpose + T14 prefetch),
    //    split-K 16
    gemm_c1<<<dim3(DD / 64, 2, C1_NZ), 256, 0, stream>>>(xh, c1_w, part);

    // 2. hidden = relu(sum partials + c1_b)  [fp32]
    reduce_partials<<<(MC * DD) / 256, 256, 0, stream>>>(
        part, c1_b, hidden, MC * DD, DD, C1_NZ, 1, 0);

    // 3. w2s = c2_w @ score_w  (row-dots)
    w2s_kernel<<<DD, 256, 0, stream>>>(c2_w, score_w, w2s);

    // 4. scores = hidden @ w2s  (constant offset dropped; rank-invariant)
    score2_kernel<<<MC, 256, 0, stream>>>(hidden, w2s, scores);

    // 5. top-16 per batch
    topk_kernel<<<BB, 128, 0, stream>>>(scores, topIdx);

    // 6. compSel partials: hidden[sel] @ c2_w  (32 x 1024, K=1024, split-K 16)
    gemm128<2><<<dim3(DD / 128, 1, 16), 256, 0, stream>>>(
        hidden, c2_w, nullptr, part, MSEL, DD, DD, topIdx, 0);

    // 6b. compSel = sum partials + c2_b  [fp32]
    reduce_partials<<<(MSEL * DD) / 256, 256, 0, stream>>>(
        part, c2_b, compSel, MSEL * DD, DD, 16, 0, 0);

    // 7. sqkv partials: compSel @ qkv_w  (32 x 3072, K=1024, split-K 16)
    gemm128<0><<<dim3(3 * DD / 128, 1, 16), 256, 0, stream>>>(
        compSel, qkv_w, nullptr, part, MSEL, 3 * DD, DD, nullptr, 0);

    // 7b. sqkv = sum partials + qkv_b  [f16]
    reduce_partials<<<(MSEL * 3 * DD + 255) / 256, 256, 0, stream>>>(
        part, qkv_b, sqkvb, MSEL * 3 * DD, 3 * DD, 16, 0, 1);

    // 8. weight transposes (A2 partials now dead)
    transpose_conv<<<dim3(3 * DD / 32, DD / 32), 256, 0, stream>>>(
        qkv_w, qkv_wT, DD, 3 * DD);
    transpose_conv<<<dim3(DD / 32, DD / 32), 256, 0, stream>>>(
        out_w, out_wT, DD, DD);

    // 9. qkv = x @ qkv_w + qkv_b  [f16 MFMA, f16 out, XCD-swizzled]
    gemm_f16<1><<<dim3(3 * DD / 128, MROWS / 128), 256, 0, stream>>>(
        xh, qkv_wT, qkv_b, (float*)qkvb, MROWS, 3 * DD, DD);

    // 10. attention on matrix cores (f16 I/O)
    attn_mfma<<<BB * HH * (SS / QT), 256, 0, stream>>>(
        qkvb, (const f16*)sqkvb, attnf);

    // 11. out = attn @ out_w + out_b  [f16 MFMA, fp32 out, XCD-swizzled]
    gemm_f16<0><<<dim3(DD / 128, MROWS / 128), 256, 0, stream>>>(
        attnf, out_wT, out_b, out, MROWS, DD, DD);
}